// Round 11
// baseline (1718.600 us; speedup 1.0000x reference)
//
#include <hip/hip_runtime.h>

typedef __bf16 bf16x8 __attribute__((ext_vector_type(8)));
typedef __bf16 bf16x4 __attribute__((ext_vector_type(4)));
typedef float  f32x4  __attribute__((ext_vector_type(4)));

#define N_NODES  50000
#define N_EDGES  500000
#define EB       64          // edges per k_msg block (f32 mF = 32 KB -> 4 blocks/CU)
#define EP       500096      // padded edge count (multiple of EB)
#define NCH      12          // 16B chunks per edge row (96 bf16)
#define N_GRAPHS 1024
#define NF       128
#define IN_DIM   92
#define N_LAYERS 5
#define SPANMAX  192

__device__ __forceinline__ float sigmoidf_(float x) { return 1.0f / (1.0f + __expf(-x)); }
__device__ __forceinline__ float softplusf_(float x) {
    return fmaxf(x, 0.0f) + __logf(1.0f + __expf(-fabsf(x)));
}
__device__ __forceinline__ float siluf_(float x) { return x * sigmoidf_(x); }

// ---------------------------------------------------------------------------
// Fold the edge-MLP second stage into layer weights (see R6 notes).
// ---------------------------------------------------------------------------
__global__ void __launch_bounds__(256) k_fold(const float* __restrict__ Wg,
    const float* __restrict__ Wc, const float* __restrict__ rbW2,
    const float* __restrict__ rbB2, const float* __restrict__ shW2,
    const float* __restrict__ shB2, const float* __restrict__ bg,
    const float* __restrict__ bc, float* __restrict__ Wfold,
    float* __restrict__ bF) {
    int lg = blockIdx.x, l = lg >> 1, g = lg & 1;
    const float* W = (g ? Wc : Wg) + (size_t)l * 384 * 128;
    const float* bsrc = (g ? bc : bg) + l * 128;
    int tid = threadIdx.x;
    for (int idx = tid; idx < 96 * 128; idx += 256) {
        int r = idx >> 7, n = idx & 127;
        float s = 0.f;
        if (r < 64) {
            for (int o = 0; o < 64; ++o) s += rbW2[r * 64 + o] * W[(256 + o) * 128 + n];
        } else {
            int j = r - 64;
            for (int o = 0; o < 64; ++o) s += shW2[j * 64 + o] * W[(320 + o) * 128 + n];
        }
        Wfold[(size_t)lg * 12288 + idx] = s;
    }
    if (tid < 128) {
        float s = bsrc[tid];
        for (int o = 0; o < 64; ++o) s += rbB2[o] * W[(256 + o) * 128 + tid];
        for (int o = 0; o < 64; ++o) s += shB2[o] * W[(320 + o) * 128 + tid];
        bF[lg * 128 + tid] = s;
    }
}

// ---------------------------------------------------------------------------
// Weight prep: WeT = A-frags of Wfold^T; WnT = A-frags of node weights.
// ---------------------------------------------------------------------------
__global__ void __launch_bounds__(256) k_prep_w(const float* __restrict__ Wg,
                                                const float* __restrict__ Wc,
                                                const float* __restrict__ Wfold,
                                                __bf16* __restrict__ WeT,
                                                __bf16* __restrict__ WnT) {
    int t = blockIdx.x * 256 + threadIdx.x;
    if (t >= (240 + 640) * 64) return;
    int frag = t >> 6, lane = t & 63;
    int sub = lane >> 4, mm = lane & 15;
    bf16x8 v;
    if (frag < 240) {
        int lg = frag / 24; int r = frag % 24;
        int m = r / 3; int ks = r % 3;
        #pragma unroll
        for (int j = 0; j < 8; ++j) {
            int k = ks * 32 + sub * 8 + j;
            v[j] = (__bf16)Wfold[(size_t)lg * 12288 + (size_t)k * 128 + m * 16 + mm];
        }
        *(bf16x8*)(WeT + (size_t)frag * 512 + lane * 8) = v;
    } else {
        int f2 = frag - 240;
        int l = f2 / 128; int r = f2 % 128;
        int m = r >> 2; int ks = r & 3;
        int F = m * 16 + mm;
        #pragma unroll
        for (int j = 0; j < 8; ++j) {
            int k = ks * 32 + sub * 8 + j;
            float val;
            if      (F < 128) val = Wg[(size_t)l*384*128 + (size_t)k*128 + F];
            else if (F < 256) val = Wc[(size_t)l*384*128 + (size_t)k*128 + (F-128)];
            else if (F < 384) val = Wg[(size_t)l*384*128 + (size_t)(128+k)*128 + (F-256)];
            else              val = Wc[(size_t)l*384*128 + (size_t)(128+k)*128 + (F-384)];
            v[j] = (__bf16)val;
        }
        *(bf16x8*)(WnT + (size_t)f2 * 512 + lane * 8) = v;
    }
}

// ---------------------------------------------------------------------------
// CSR build
// ---------------------------------------------------------------------------
__global__ void __launch_bounds__(256) k_deg(const int* __restrict__ dstI,
                                             int* __restrict__ deg) {
    int e = blockIdx.x * 256 + threadIdx.x;
    if (e < N_EDGES) atomicAdd(&deg[dstI[e]], 1);
}

__global__ void __launch_bounds__(1024) k_scan(const int* __restrict__ deg,
                                               int* __restrict__ cursor) {
    __shared__ int ps[1024];
    int t = threadIdx.x;
    const int C = (N_NODES + 1023) / 1024;
    int base = t * C;
    int s = 0;
    for (int i = 0; i < C; ++i) { int idx = base + i; if (idx < N_NODES) s += deg[idx]; }
    ps[t] = s;
    __syncthreads();
    for (int off = 1; off < 1024; off <<= 1) {
        int v = 0;
        if (t >= off) v = ps[t - off];
        __syncthreads();
        if (t >= off) ps[t] += v;
        __syncthreads();
    }
    int run = (t > 0) ? ps[t - 1] : 0;
    for (int i = 0; i < C; ++i) {
        int idx = base + i;
        if (idx < N_NODES) { cursor[idx] = run; run += deg[idx]; }
    }
}

__global__ void __launch_bounds__(256) k_scatter(const int* __restrict__ srcI,
                                                 const int* __restrict__ dstI,
                                                 int* __restrict__ cursor,
                                                 int* __restrict__ perm,
                                                 int* __restrict__ dstS,
                                                 int* __restrict__ srcS) {
    int e = blockIdx.x * 256 + threadIdx.x;
    if (e >= N_EDGES) return;
    int d = dstI[e];
    int p = atomicAdd(&cursor[d], 1);
    perm[p] = e;
    dstS[p] = d;
    srcS[p] = srcI[e];
}

// ---------------------------------------------------------------------------
// Pad entries [N_EDGES, EP): dummy dst node N_NODES, src 0, zeroed ea2 chunks.
// ---------------------------------------------------------------------------
__global__ void __launch_bounds__(128) k_pad(int* __restrict__ dstS,
                                             int* __restrict__ srcS,
                                             char* __restrict__ ea2) {
    int i = threadIdx.x;
    if (i < EP - N_EDGES) {
        dstS[N_EDGES + i] = N_NODES;
        srcS[N_EDGES + i] = 0;
        uint4 z = {0, 0, 0, 0};
        for (int p = 0; p < NCH; ++p)
            *(uint4*)(ea2 + ((size_t)p * EP + N_EDGES + i) * 16) = z;
    }
}

// ---------------------------------------------------------------------------
// Atom embedding: h = x @ W_emb + b_emb (f32)
// ---------------------------------------------------------------------------
__global__ void __launch_bounds__(256) k_embed(const float* __restrict__ x,
                                               const float* __restrict__ W,
                                               const float* __restrict__ b,
                                               float* __restrict__ h) {
    int tid = threadIdx.x;
    int f = tid & 127;
    int nb = blockIdx.x * 8 + (tid >> 7) * 4;   // 8 nodes per block
    const float* x0 = x + (size_t)nb * IN_DIM;
    float a0 = b[f], a1 = a0, a2 = a0, a3 = a0;
    #pragma unroll 4
    for (int k = 0; k < IN_DIM; ++k) {
        float wv = W[k * NF + f];
        a0 = fmaf(x0[k], wv, a0);
        a1 = fmaf(x0[IN_DIM + k], wv, a1);
        a2 = fmaf(x0[2 * IN_DIM + k], wv, a2);
        a3 = fmaf(x0[3 * IN_DIM + k], wv, a3);
    }
    float accs[4] = {a0, a1, a2, a3};
    #pragma unroll
    for (int r = 0; r < 4; ++r)
        h[(size_t)(nb + r) * NF + f] = accs[r];
}

// ---------------------------------------------------------------------------
// Edge hidden features eh[e][96], dst-sorted, transposed chunk-plane layout.
// ---------------------------------------------------------------------------
__global__ void __launch_bounds__(256) k_edge(const float* __restrict__ sh,
    const float* __restrict__ dist, const int* __restrict__ perm,
    const float* __restrict__ shW1, const float* __restrict__ shB1,
    const float* __restrict__ rbW1, const float* __restrict__ rbB1,
    char* __restrict__ ea2) {
    __shared__ float wf[4480];
    int tid = threadIdx.x;
    int p = blockIdx.x * 256 + tid;
    bool pv = p < N_EDGES;
    int e = pv ? perm[p] : 0;
    float dv = dist[e];
    float shv[9];
    #pragma unroll
    for (int i = 0; i < 9; ++i) shv[i] = sh[(size_t)e * 9 + i];
    for (int i = tid; i < 288;  i += 256) wf[i]        = shW1[i];
    for (int i = tid; i < 32;   i += 256) wf[288 + i]  = shB1[i];
    for (int i = tid; i < 4096; i += 256) wf[320 + i]  = rbW1[i];
    for (int i = tid; i < 64;   i += 256) wf[4416 + i] = rbB1[i];
    __syncthreads();
    if (!pv) return;

    const float* W1 = wf + 320; const float* B1 = wf + 4416;
    float invd = 1.0f / dv;
    const float step = (1.4f - 0.125f) / 63.0f;
    const float gam = 1.0f / (step * step);
    float hid[64];
    #pragma unroll
    for (int j = 0; j < 64; ++j) hid[j] = B1[j];
    for (int i = 0; i < 64; ++i) {
        float c = 0.125f + i * step;
        float d = invd - c;
        float r = __expf(-gam * d * d);
        #pragma unroll
        for (int j = 0; j < 64; ++j) hid[j] += r * W1[i * 64 + j];
    }
    #pragma unroll
    for (int o8 = 0; o8 < 8; ++o8) {
        bf16x8 v;
        #pragma unroll
        for (int j = 0; j < 8; ++j) v[j] = (__bf16)siluf_(hid[o8 * 8 + j]);
        *(bf16x8*)(ea2 + ((size_t)o8 * EP + p) * 16) = v;
    }
    const float* sW1 = wf; const float* sB1 = wf + 288;
    float h2[32];
    #pragma unroll
    for (int j = 0; j < 32; ++j) h2[j] = sB1[j];
    #pragma unroll
    for (int i = 0; i < 9; ++i) {
        float si = shv[i];
        #pragma unroll
        for (int j = 0; j < 32; ++j) h2[j] += si * sW1[i * 32 + j];
    }
    #pragma unroll
    for (int o8 = 0; o8 < 4; ++o8) {
        bf16x8 v;
        #pragma unroll
        for (int j = 0; j < 8; ++j) v[j] = (__bf16)siluf_(h2[o8 * 8 + j]);
        *(bf16x8*)(ea2 + ((size_t)(8 + o8) * EP + p) * 16) = v;
    }
}

// ---------------------------------------------------------------------------
// Per-node GEMM: NBd[node][256] = [h@Wg_d + bFg | h@Wc_d + bFc] (TD = f32/bf16)
//                NBs[node][256] = [h@Wg_s | h@Wc_s]             (bf16)
// Reads h (f32), converts to bf16 fragments in-register.
// ---------------------------------------------------------------------------
template <typename TD>
__global__ void __launch_bounds__(256) k_node(const float* __restrict__ h,
                                              const __bf16* __restrict__ WnT,
                                              const float* __restrict__ bgl,
                                              const float* __restrict__ bcl,
                                              TD* __restrict__ NBd,
                                              __bf16* __restrict__ NBs, int layer) {
    int tid = threadIdx.x, lane = tid & 63, w = tid >> 6;
    int sub = lane >> 4, rA = lane & 15;
    int node0 = blockIdx.x * 32;
    bf16x8 Bf[2][4];
    #pragma unroll
    for (int nt = 0; nt < 2; ++nt)
        #pragma unroll
        for (int ks = 0; ks < 4; ++ks) {
            int node = min(node0 + nt * 16 + rA, N_NODES - 1);
            const float* hr = h + (size_t)node * 128 + ks * 32 + sub * 8;
            f32x4 u0 = *(const f32x4*)hr;
            f32x4 u1 = *(const f32x4*)(hr + 4);
            bf16x8 bv;
            bv[0] = (__bf16)u0[0]; bv[1] = (__bf16)u0[1];
            bv[2] = (__bf16)u0[2]; bv[3] = (__bf16)u0[3];
            bv[4] = (__bf16)u1[0]; bv[5] = (__bf16)u1[1];
            bv[6] = (__bf16)u1[2]; bv[7] = (__bf16)u1[3];
            Bf[nt][ks] = bv;
        }
    const __bf16* Wbase = WnT + (size_t)layer * 128 * 512;
    f32x4 acc[8][2];
    f32x4 zz = {0.f, 0.f, 0.f, 0.f};
    #pragma unroll
    for (int mt = 0; mt < 8; ++mt) { acc[mt][0] = zz; acc[mt][1] = zz; }
    for (int mt = 0; mt < 8; ++mt) {
        int gm = w * 8 + mt;
        bf16x8 Af[4];
        #pragma unroll
        for (int ks = 0; ks < 4; ++ks)
            Af[ks] = *(const bf16x8*)(Wbase + (size_t)(gm * 4 + ks) * 512 + lane * 8);
        #pragma unroll
        for (int nt = 0; nt < 2; ++nt) {
            f32x4 a = acc[mt][nt];
            #pragma unroll
            for (int ks = 0; ks < 4; ++ks)
                a = __builtin_amdgcn_mfma_f32_16x16x32_bf16(Af[ks], Bf[nt][ks], a, 0, 0, 0);
            acc[mt][nt] = a;
        }
    }
    #pragma unroll
    for (int mt = 0; mt < 8; ++mt) {
        int F = (w * 8 + mt) * 16 + sub * 4;
        f32x4 bias = zz;
        if (w == 0)      bias = *(const f32x4*)(bgl + F);
        else if (w == 1) bias = *(const f32x4*)(bcl + (F - 128));
        #pragma unroll
        for (int nt = 0; nt < 2; ++nt) {
            int node = node0 + nt * 16 + rA;
            if (node >= N_NODES) continue;
            f32x4 vv = acc[mt][nt];
            vv[0] += bias[0]; vv[1] += bias[1]; vv[2] += bias[2]; vv[3] += bias[3];
            if (w < 2) {
                if constexpr (sizeof(TD) == 4) {
                    *(f32x4*)(NBd + (size_t)node * 256 + F) = vv;
                } else {
                    bf16x4 bv;
                    bv[0] = (__bf16)vv[0]; bv[1] = (__bf16)vv[1];
                    bv[2] = (__bf16)vv[2]; bv[3] = (__bf16)vv[3];
                    *(bf16x4*)((__bf16*)NBd + (size_t)node * 256 + F) = bv;
                }
            } else {
                bf16x4 bv;
                bv[0] = (__bf16)vv[0]; bv[1] = (__bf16)vv[1];
                bv[2] = (__bf16)vv[2]; bv[3] = (__bf16)vv[3];
                *(bf16x4*)(NBs + (size_t)node * 256 + (F - 256)) = bv;
            }
        }
    }
}

template <typename TD>
__device__ __forceinline__ f32x4 ld_nb4(const TD* p) {
    if constexpr (sizeof(TD) == 4) {
        return *(const f32x4*)p;
    } else {
        bf16x4 t = *(const bf16x4*)p;
        f32x4 r;
        r[0] = (float)t[0]; r[1] = (float)t[1]; r[2] = (float)t[2]; r[3] = (float)t[3];
        return r;
    }
}

// ---------------------------------------------------------------------------
// Message layer, dst-sorted, all blocks full (padded edges -> dummy node).
// EB=64: f32 mF = 32 KB, total LDS ~34 KB -> 4 blocks/CU;
// __launch_bounds__(512,8) pins 8 waves/SIMD (VGPR cap 64, body uses ~52).
// ---------------------------------------------------------------------------
template <typename TD>
__global__ void __launch_bounds__(512, 8) k_msg(
    const char* __restrict__ ea2, const int* __restrict__ dstS,
    const int* __restrict__ srcS, const __bf16* __restrict__ WeT,
    const TD* __restrict__ NBd, const __bf16* __restrict__ NBs,
    float* __restrict__ h, int layer)
{
    __shared__ __align__(16) float mF[EB * 128];   // 32 KB messages (XOR-swizzled)
    __shared__ int rs[SPANMAX], re[SPANMAX];
    int tid = threadIdx.x, lane = tid & 63, w = tid >> 6;
    int sub = lane >> 4, rA = lane & 15;
    int e0 = blockIdx.x * EB;
    int F = w * 16 + sub * 4;
    int n0 = dstS[e0];

    // run-boundary tables (gap-fill by run-starter; no init barrier needed)
    if (tid < EB) {
        int d = dstS[e0 + tid];
        int di = min(d - n0, SPANMAX - 1);
        if (tid == 0 || dstS[e0 + tid - 1] != d) {
            rs[di] = tid;
            if (tid > 0) {
                int dp = dstS[e0 + tid - 1];
                for (int g = dp + 1; g < d && (g - n0) < SPANMAX; ++g) {
                    rs[g - n0] = 0; re[g - n0] = 0;
                }
            }
        }
        if (tid == EB - 1 || dstS[e0 + tid + 1] != d) re[di] = tid + 1;
    }

    // folded edge-weight A-frags (registers, L2-resident)
    bf16x8 Ag[3], Ac[3];
    {
        const __bf16* bg_ = WeT + (size_t)(((layer * 2 + 0) * 8 + w) * 3) * 512;
        const __bf16* bc_ = WeT + (size_t)(((layer * 2 + 1) * 8 + w) * 3) * 512;
        #pragma unroll
        for (int ks = 0; ks < 3; ++ks) {
            Ag[ks] = *(const bf16x8*)(bg_ + ks * 512 + lane * 8);
            Ac[ks] = *(const bf16x8*)(bc_ + ks * 512 + lane * 8);
        }
    }

    // hoisted loop-invariant bases
    const char* eb0 = ea2 + ((size_t)(0 + sub) * EP + e0 + rA) * 16;
    const char* eb1 = ea2 + ((size_t)(4 + sub) * EP + e0 + rA) * 16;
    const char* eb2 = ea2 + ((size_t)(8 + sub) * EP + e0 + rA) * 16;
    const int* srcp = srcS + e0 + rA;
    const int* dstp = dstS + e0 + rA;
    char* mfp = (char*)mF + rA * 512 + ((w * 64 + sub * 16) ^ ((rA & 7) << 4));

    f32x4 zz = {0.f, 0.f, 0.f, 0.f};
    // depth-2 pipelined register sets (indices fold to constants under unroll)
    bf16x8 bfr[2][3];
    bf16x4 gs[2], cs[2];
    f32x4  gd[2], cd[2];

    // prologue: load nt=0
    {
        int src = srcp[0], dstc = min(dstp[0], N_NODES - 1);
        bfr[0][0] = *(const bf16x8*)(eb0);
        bfr[0][1] = *(const bf16x8*)(eb1);
        bfr[0][2] = *(const bf16x8*)(eb2);
        gs[0] = *(const bf16x4*)(NBs + (size_t)src * 256 + F);
        cs[0] = *(const bf16x4*)(NBs + (size_t)src * 256 + 128 + F);
        gd[0] = ld_nb4(NBd + (size_t)dstc * 256 + F);
        cd[0] = ld_nb4(NBd + (size_t)dstc * 256 + 128 + F);
    }
    #pragma unroll
    for (int nt = 0; nt < EB / 16; ++nt) {
        int cur = nt & 1, nxt = cur ^ 1;
        if (nt + 1 < EB / 16) {   // prefetch next sub-tile
            int src = srcp[(nt + 1) * 16], dstc = min(dstp[(nt + 1) * 16], N_NODES - 1);
            bfr[nxt][0] = *(const bf16x8*)(eb0 + (nt + 1) * 256);
            bfr[nxt][1] = *(const bf16x8*)(eb1 + (nt + 1) * 256);
            bfr[nxt][2] = *(const bf16x8*)(eb2 + (nt + 1) * 256);
            gs[nxt] = *(const bf16x4*)(NBs + (size_t)src * 256 + F);
            cs[nxt] = *(const bf16x4*)(NBs + (size_t)src * 256 + 128 + F);
            gd[nxt] = ld_nb4(NBd + (size_t)dstc * 256 + F);
            cd[nxt] = ld_nb4(NBd + (size_t)dstc * 256 + 128 + F);
        }
        f32x4 aG = zz, aC = zz;
        #pragma unroll
        for (int ks = 0; ks < 3; ++ks) {
            aG = __builtin_amdgcn_mfma_f32_16x16x32_bf16(Ag[ks], bfr[cur][ks], aG, 0, 0, 0);
            aC = __builtin_amdgcn_mfma_f32_16x16x32_bf16(Ac[ks], bfr[cur][ks], aC, 0, 0, 0);
        }
        f32x4 mv;
        #pragma unroll
        for (int r = 0; r < 4; ++r) {
            float gi = aG[r] + gd[cur][r] + (float)gs[cur][r];
            float ci = aC[r] + cd[cur][r] + (float)cs[cur][r];
            mv[r] = sigmoidf_(gi) * softplusf_(ci);
        }
        *(f32x4*)(mfp + nt * 8192) = mv;
    }
    __syncthreads();
    // segment-sum over runs -> h (16B feature granularity)
    int span = min(dstS[e0 + EB - 1] - n0 + 1, SPANMAX);
    int items = span * 32;
    for (int it = tid; it < items; it += 512) {
        int ln = it >> 5, fq = it & 31;
        int rs_ = rs[ln], re_ = re[ln];
        f32x4 s = zz;
        for (int e = rs_; e < re_; ++e) {
            f32x4 v = *(const f32x4*)((char*)mF + e * 512 + ((fq * 16) ^ ((e & 7) << 4)));
            s[0] += v[0]; s[1] += v[1]; s[2] += v[2]; s[3] += v[3];
        }
        int node = n0 + ln;
        float* dp = h + (size_t)node * 128 + fq * 4;
        if (ln == 0 || ln == span - 1) {
            atomicAdd(dp + 0, s[0]); atomicAdd(dp + 1, s[1]);
            atomicAdd(dp + 2, s[2]); atomicAdd(dp + 3, s[3]);
        } else {
            dp[0] += s[0]; dp[1] += s[1]; dp[2] += s[2]; dp[3] += s[3];
        }
    }
}

// ---------------------------------------------------------------------------
// Readout
// ---------------------------------------------------------------------------
__global__ void __launch_bounds__(128) k_readout(const float* __restrict__ h,
    const int* __restrict__ batch, const float* __restrict__ W1,
    const float* __restrict__ b1, const float* __restrict__ W2,
    const float* __restrict__ b2, float* __restrict__ out) {
    int g = blockIdx.x, tid = threadIdx.x;
    __shared__ int se[2];
    __shared__ float pl[NF];
    __shared__ float red[2];
    if (tid < 2) {
        int target = g + tid;
        int lo = 0, hi = N_NODES;
        while (lo < hi) { int mid = (lo + hi) >> 1; if (batch[mid] < target) lo = mid + 1; else hi = mid; }
        se[tid] = lo;
    }
    __syncthreads();
    int s = se[0], e = se[1];
    float sum = 0.0f;
    for (int n = s; n < e; ++n) sum += h[(size_t)n * NF + tid];
    float cnt = (float)max(e - s, 1);
    pl[tid] = sum / cnt;
    __syncthreads();
    float acc = b1[tid];
    for (int c = 0; c < NF; ++c) acc += pl[c] * W1[c * NF + tid];
    float hid = siluf_(acc);
    float v = hid * W2[tid];
    #pragma unroll
    for (int off = 32; off > 0; off >>= 1) v += __shfl_down(v, off);
    if ((tid & 63) == 0) red[tid >> 6] = v;
    __syncthreads();
    if (tid == 0) out[g] = red[0] + red[1] + b2[0];
}

// ---------------------------------------------------------------------------
extern "C" void kernel_launch(void* const* d_in, const int* in_sizes, int n_in,
                              void* d_out, int out_size, void* d_ws, size_t ws_size,
                              hipStream_t stream) {
    const float* x     = (const float*)d_in[0];
    const int*   eidx  = (const int*)d_in[1];
    const float* sh    = (const float*)d_in[2];
    const float* edist = (const float*)d_in[3];
    const int*   batch = (const int*)d_in[4];
    const float* W_emb = (const float*)d_in[5];
    const float* b_emb = (const float*)d_in[6];
    const float* shW1  = (const float*)d_in[7];
    const float* shB1  = (const float*)d_in[8];
    const float* shW2  = (const float*)d_in[9];
    const float* shB2  = (const float*)d_in[10];
    const float* rbW1  = (const float*)d_in[11];
    const float* rbB1  = (const float*)d_in[12];
    const float* rbW2  = (const float*)d_in[13];
    const float* rbB2  = (const float*)d_in[14];
    const float* Wg    = (const float*)d_in[15];
    const float* bg    = (const float*)d_in[16];
    const float* Wc    = (const float*)d_in[17];
    const float* bc    = (const float*)d_in[18];
    const float* fcW1  = (const float*)d_in[19];
    const float* fcb1  = (const float*)d_in[20];
    const float* fcW2  = (const float*)d_in[21];
    const float* fcb2  = (const float*)d_in[22];
    const int* srcI = eidx;
    const int* dstI = eidx + N_EDGES;

    char* ws = (char*)d_ws;
    float*  h     = (float*)(ws + 0);              // 25,600,512 (50001 rows; last = dummy)
    char*   ea2   = (char*)(ws + 25600512);        // 96,018,432 (12 planes x EP x 16B)
    int*    dstS  = (int*)(ws + 121618944);        //  2,000,384 (EP entries)
    int*    srcS  = (int*)(ws + 123619328);        //  2,000,384
    int*    deg   = (int*)(ws + 125619712);        //    200,000
    int*    curs  = (int*)(ws + 125819712);        //    200,000
    int*    perm  = (int*)(ws + 126019712);        //  2,000,000
    __bf16* WeT   = (__bf16*)(ws + 128019712);     //    245,760
    __bf16* WnT   = (__bf16*)(ws + 128265472);     //    655,360
    float*  Wfold = (float*)(ws + 128920832);      //    491,520
    float*  bF    = (float*)(ws + 129412352);      //      5,120
    __bf16* NBs   = (__bf16*)(ws + 129417472);     // 25,600,000
    void*   NBd   = (void*)(ws + 155017472);       // 51.2 MB (f32) or 25.6 MB (bf16)
    bool nbf32 = (ws_size >= 206217472ULL);

    hipMemsetAsync(deg, 0, (size_t)N_NODES * sizeof(int), stream);
    k_fold<<<10, 256, 0, stream>>>(Wg, Wc, rbW2, rbB2, shW2, shB2, bg, bc, Wfold, bF);
    k_prep_w<<<220, 256, 0, stream>>>(Wg, Wc, Wfold, WeT, WnT);
    k_embed<<<N_NODES / 8, 256, 0, stream>>>(x, W_emb, b_emb, h);
    k_deg<<<(N_EDGES + 255) / 256, 256, 0, stream>>>(dstI, deg);
    k_scan<<<1, 1024, 0, stream>>>(deg, curs);
    k_scatter<<<(N_EDGES + 255) / 256, 256, 0, stream>>>(srcI, dstI, curs, perm, dstS, srcS);
    k_edge<<<(N_EDGES + 255) / 256, 256, 0, stream>>>(sh, edist, perm, shW1, shB1,
                                                      rbW1, rbB1, ea2);
    k_pad<<<1, 128, 0, stream>>>(dstS, srcS, ea2);
    for (int l = 0; l < N_LAYERS; ++l) {
        const float* bgF = bF + (l * 2 + 0) * 128;
        const float* bcF = bF + (l * 2 + 1) * 128;
        if (nbf32) {
            k_node<float><<<(N_NODES + 31) / 32, 256, 0, stream>>>(
                h, WnT, bgF, bcF, (float*)NBd, NBs, l);
            k_msg<float><<<EP / EB, 512, 0, stream>>>(
                ea2, dstS, srcS, WeT, (const float*)NBd, NBs, h, l);
        } else {
            k_node<__bf16><<<(N_NODES + 31) / 32, 256, 0, stream>>>(
                h, WnT, bgF, bcF, (__bf16*)NBd, NBs, l);
            k_msg<__bf16><<<EP / EB, 512, 0, stream>>>(
                ea2, dstS, srcS, WeT, (const __bf16*)NBd, NBs, h, l);
        }
    }
    k_readout<<<N_GRAPHS, 128, 0, stream>>>(h, batch, fcW1, fcb1, fcW2, fcb2, (float*)d_out);
}

// Round 12
// 1314.449 us; speedup vs baseline: 1.3075x; 1.3075x over previous
//
#include <hip/hip_runtime.h>

typedef __bf16 bf16x8 __attribute__((ext_vector_type(8)));
typedef __bf16 bf16x4 __attribute__((ext_vector_type(4)));
typedef float  f32x4  __attribute__((ext_vector_type(4)));

#define N_NODES  50000
#define N_EDGES  500000
#define EB       64          // edges per k_msg block (f32 mF = 32 KB -> 4 blocks/CU)
#define EP       500096      // padded edge count (multiple of EB)
#define NCH      12          // 16B chunks per edge row (96 bf16)
#define N_GRAPHS 1024
#define NF       128
#define IN_DIM   92
#define N_LAYERS 5
#define SPANMAX  192

__device__ __forceinline__ float sigmoidf_(float x) { return 1.0f / (1.0f + __expf(-x)); }
__device__ __forceinline__ float softplusf_(float x) {
    return fmaxf(x, 0.0f) + __logf(1.0f + __expf(-fabsf(x)));
}
__device__ __forceinline__ float siluf_(float x) { return x * sigmoidf_(x); }

// ---------------------------------------------------------------------------
// Fold the edge-MLP second stage into layer weights (see R6 notes).
// ---------------------------------------------------------------------------
__global__ void __launch_bounds__(256) k_fold(const float* __restrict__ Wg,
    const float* __restrict__ Wc, const float* __restrict__ rbW2,
    const float* __restrict__ rbB2, const float* __restrict__ shW2,
    const float* __restrict__ shB2, const float* __restrict__ bg,
    const float* __restrict__ bc, float* __restrict__ Wfold,
    float* __restrict__ bF) {
    int lg = blockIdx.x, l = lg >> 1, g = lg & 1;
    const float* W = (g ? Wc : Wg) + (size_t)l * 384 * 128;
    const float* bsrc = (g ? bc : bg) + l * 128;
    int tid = threadIdx.x;
    for (int idx = tid; idx < 96 * 128; idx += 256) {
        int r = idx >> 7, n = idx & 127;
        float s = 0.f;
        if (r < 64) {
            for (int o = 0; o < 64; ++o) s += rbW2[r * 64 + o] * W[(256 + o) * 128 + n];
        } else {
            int j = r - 64;
            for (int o = 0; o < 64; ++o) s += shW2[j * 64 + o] * W[(320 + o) * 128 + n];
        }
        Wfold[(size_t)lg * 12288 + idx] = s;
    }
    if (tid < 128) {
        float s = bsrc[tid];
        for (int o = 0; o < 64; ++o) s += rbB2[o] * W[(256 + o) * 128 + tid];
        for (int o = 0; o < 64; ++o) s += shB2[o] * W[(320 + o) * 128 + tid];
        bF[lg * 128 + tid] = s;
    }
}

// ---------------------------------------------------------------------------
// Weight prep: WeT = A-frags of Wfold^T; WnT = A-frags of node weights.
// ---------------------------------------------------------------------------
__global__ void __launch_bounds__(256) k_prep_w(const float* __restrict__ Wg,
                                                const float* __restrict__ Wc,
                                                const float* __restrict__ Wfold,
                                                __bf16* __restrict__ WeT,
                                                __bf16* __restrict__ WnT) {
    int t = blockIdx.x * 256 + threadIdx.x;
    if (t >= (240 + 640) * 64) return;
    int frag = t >> 6, lane = t & 63;
    int sub = lane >> 4, mm = lane & 15;
    bf16x8 v;
    if (frag < 240) {
        int lg = frag / 24; int r = frag % 24;
        int m = r / 3; int ks = r % 3;
        #pragma unroll
        for (int j = 0; j < 8; ++j) {
            int k = ks * 32 + sub * 8 + j;
            v[j] = (__bf16)Wfold[(size_t)lg * 12288 + (size_t)k * 128 + m * 16 + mm];
        }
        *(bf16x8*)(WeT + (size_t)frag * 512 + lane * 8) = v;
    } else {
        int f2 = frag - 240;
        int l = f2 / 128; int r = f2 % 128;
        int m = r >> 2; int ks = r & 3;
        int F = m * 16 + mm;
        #pragma unroll
        for (int j = 0; j < 8; ++j) {
            int k = ks * 32 + sub * 8 + j;
            float val;
            if      (F < 128) val = Wg[(size_t)l*384*128 + (size_t)k*128 + F];
            else if (F < 256) val = Wc[(size_t)l*384*128 + (size_t)k*128 + (F-128)];
            else if (F < 384) val = Wg[(size_t)l*384*128 + (size_t)(128+k)*128 + (F-256)];
            else              val = Wc[(size_t)l*384*128 + (size_t)(128+k)*128 + (F-384)];
            v[j] = (__bf16)val;
        }
        *(bf16x8*)(WnT + (size_t)f2 * 512 + lane * 8) = v;
    }
}

// ---------------------------------------------------------------------------
// CSR build
// ---------------------------------------------------------------------------
__global__ void __launch_bounds__(256) k_deg(const int* __restrict__ dstI,
                                             int* __restrict__ deg) {
    int e = blockIdx.x * 256 + threadIdx.x;
    if (e < N_EDGES) atomicAdd(&deg[dstI[e]], 1);
}

__global__ void __launch_bounds__(1024) k_scan(const int* __restrict__ deg,
                                               int* __restrict__ cursor) {
    __shared__ int ps[1024];
    int t = threadIdx.x;
    const int C = (N_NODES + 1023) / 1024;
    int base = t * C;
    int s = 0;
    for (int i = 0; i < C; ++i) { int idx = base + i; if (idx < N_NODES) s += deg[idx]; }
    ps[t] = s;
    __syncthreads();
    for (int off = 1; off < 1024; off <<= 1) {
        int v = 0;
        if (t >= off) v = ps[t - off];
        __syncthreads();
        if (t >= off) ps[t] += v;
        __syncthreads();
    }
    int run = (t > 0) ? ps[t - 1] : 0;
    for (int i = 0; i < C; ++i) {
        int idx = base + i;
        if (idx < N_NODES) { cursor[idx] = run; run += deg[idx]; }
    }
}

__global__ void __launch_bounds__(256) k_scatter(const int* __restrict__ srcI,
                                                 const int* __restrict__ dstI,
                                                 int* __restrict__ cursor,
                                                 int* __restrict__ perm,
                                                 int* __restrict__ dstS,
                                                 int* __restrict__ srcS) {
    int e = blockIdx.x * 256 + threadIdx.x;
    if (e >= N_EDGES) return;
    int d = dstI[e];
    int p = atomicAdd(&cursor[d], 1);
    perm[p] = e;
    dstS[p] = d;
    srcS[p] = srcI[e];
}

// ---------------------------------------------------------------------------
// Pad entries [N_EDGES, EP): dummy dst node N_NODES, src 0, zeroed ea2 chunks.
// ---------------------------------------------------------------------------
__global__ void __launch_bounds__(128) k_pad(int* __restrict__ dstS,
                                             int* __restrict__ srcS,
                                             char* __restrict__ ea2) {
    int i = threadIdx.x;
    if (i < EP - N_EDGES) {
        dstS[N_EDGES + i] = N_NODES;
        srcS[N_EDGES + i] = 0;
        uint4 z = {0, 0, 0, 0};
        for (int p = 0; p < NCH; ++p)
            *(uint4*)(ea2 + ((size_t)p * EP + N_EDGES + i) * 16) = z;
    }
}

// ---------------------------------------------------------------------------
// Atom embedding: h = x @ W_emb + b_emb (f32)
// ---------------------------------------------------------------------------
__global__ void __launch_bounds__(256) k_embed(const float* __restrict__ x,
                                               const float* __restrict__ W,
                                               const float* __restrict__ b,
                                               float* __restrict__ h) {
    int tid = threadIdx.x;
    int f = tid & 127;
    int nb = blockIdx.x * 8 + (tid >> 7) * 4;   // 8 nodes per block
    const float* x0 = x + (size_t)nb * IN_DIM;
    float a0 = b[f], a1 = a0, a2 = a0, a3 = a0;
    #pragma unroll 4
    for (int k = 0; k < IN_DIM; ++k) {
        float wv = W[k * NF + f];
        a0 = fmaf(x0[k], wv, a0);
        a1 = fmaf(x0[IN_DIM + k], wv, a1);
        a2 = fmaf(x0[2 * IN_DIM + k], wv, a2);
        a3 = fmaf(x0[3 * IN_DIM + k], wv, a3);
    }
    float accs[4] = {a0, a1, a2, a3};
    #pragma unroll
    for (int r = 0; r < 4; ++r)
        h[(size_t)(nb + r) * NF + f] = accs[r];
}

// ---------------------------------------------------------------------------
// Edge hidden features eh[e][96], dst-sorted, transposed chunk-plane layout.
// ---------------------------------------------------------------------------
__global__ void __launch_bounds__(256) k_edge(const float* __restrict__ sh,
    const float* __restrict__ dist, const int* __restrict__ perm,
    const float* __restrict__ shW1, const float* __restrict__ shB1,
    const float* __restrict__ rbW1, const float* __restrict__ rbB1,
    char* __restrict__ ea2) {
    __shared__ float wf[4480];
    int tid = threadIdx.x;
    int p = blockIdx.x * 256 + tid;
    bool pv = p < N_EDGES;
    int e = pv ? perm[p] : 0;
    float dv = dist[e];
    float shv[9];
    #pragma unroll
    for (int i = 0; i < 9; ++i) shv[i] = sh[(size_t)e * 9 + i];
    for (int i = tid; i < 288;  i += 256) wf[i]        = shW1[i];
    for (int i = tid; i < 32;   i += 256) wf[288 + i]  = shB1[i];
    for (int i = tid; i < 4096; i += 256) wf[320 + i]  = rbW1[i];
    for (int i = tid; i < 64;   i += 256) wf[4416 + i] = rbB1[i];
    __syncthreads();
    if (!pv) return;

    const float* W1 = wf + 320; const float* B1 = wf + 4416;
    float invd = 1.0f / dv;
    const float step = (1.4f - 0.125f) / 63.0f;
    const float gam = 1.0f / (step * step);
    float hid[64];
    #pragma unroll
    for (int j = 0; j < 64; ++j) hid[j] = B1[j];
    for (int i = 0; i < 64; ++i) {
        float c = 0.125f + i * step;
        float d = invd - c;
        float r = __expf(-gam * d * d);
        #pragma unroll
        for (int j = 0; j < 64; ++j) hid[j] += r * W1[i * 64 + j];
    }
    #pragma unroll
    for (int o8 = 0; o8 < 8; ++o8) {
        bf16x8 v;
        #pragma unroll
        for (int j = 0; j < 8; ++j) v[j] = (__bf16)siluf_(hid[o8 * 8 + j]);
        *(bf16x8*)(ea2 + ((size_t)o8 * EP + p) * 16) = v;
    }
    const float* sW1 = wf; const float* sB1 = wf + 288;
    float h2[32];
    #pragma unroll
    for (int j = 0; j < 32; ++j) h2[j] = sB1[j];
    #pragma unroll
    for (int i = 0; i < 9; ++i) {
        float si = shv[i];
        #pragma unroll
        for (int j = 0; j < 32; ++j) h2[j] += si * sW1[i * 32 + j];
    }
    #pragma unroll
    for (int o8 = 0; o8 < 4; ++o8) {
        bf16x8 v;
        #pragma unroll
        for (int j = 0; j < 8; ++j) v[j] = (__bf16)siluf_(h2[o8 * 8 + j]);
        *(bf16x8*)(ea2 + ((size_t)(8 + o8) * EP + p) * 16) = v;
    }
}

// ---------------------------------------------------------------------------
// Per-node GEMM: NBd[node][256] = [h@Wg_d + bFg | h@Wc_d + bFc] (TD = f32/bf16)
//                NBs[node][256] = [h@Wg_s | h@Wc_s]             (bf16)
// Reads h (f32), converts to bf16 fragments in-register.
// ---------------------------------------------------------------------------
template <typename TD>
__global__ void __launch_bounds__(256) k_node(const float* __restrict__ h,
                                              const __bf16* __restrict__ WnT,
                                              const float* __restrict__ bgl,
                                              const float* __restrict__ bcl,
                                              TD* __restrict__ NBd,
                                              __bf16* __restrict__ NBs, int layer) {
    int tid = threadIdx.x, lane = tid & 63, w = tid >> 6;
    int sub = lane >> 4, rA = lane & 15;
    int node0 = blockIdx.x * 32;
    bf16x8 Bf[2][4];
    #pragma unroll
    for (int nt = 0; nt < 2; ++nt)
        #pragma unroll
        for (int ks = 0; ks < 4; ++ks) {
            int node = min(node0 + nt * 16 + rA, N_NODES - 1);
            const float* hr = h + (size_t)node * 128 + ks * 32 + sub * 8;
            f32x4 u0 = *(const f32x4*)hr;
            f32x4 u1 = *(const f32x4*)(hr + 4);
            bf16x8 bv;
            bv[0] = (__bf16)u0[0]; bv[1] = (__bf16)u0[1];
            bv[2] = (__bf16)u0[2]; bv[3] = (__bf16)u0[3];
            bv[4] = (__bf16)u1[0]; bv[5] = (__bf16)u1[1];
            bv[6] = (__bf16)u1[2]; bv[7] = (__bf16)u1[3];
            Bf[nt][ks] = bv;
        }
    const __bf16* Wbase = WnT + (size_t)layer * 128 * 512;
    f32x4 acc[8][2];
    f32x4 zz = {0.f, 0.f, 0.f, 0.f};
    #pragma unroll
    for (int mt = 0; mt < 8; ++mt) { acc[mt][0] = zz; acc[mt][1] = zz; }
    for (int mt = 0; mt < 8; ++mt) {
        int gm = w * 8 + mt;
        bf16x8 Af[4];
        #pragma unroll
        for (int ks = 0; ks < 4; ++ks)
            Af[ks] = *(const bf16x8*)(Wbase + (size_t)(gm * 4 + ks) * 512 + lane * 8);
        #pragma unroll
        for (int nt = 0; nt < 2; ++nt) {
            f32x4 a = acc[mt][nt];
            #pragma unroll
            for (int ks = 0; ks < 4; ++ks)
                a = __builtin_amdgcn_mfma_f32_16x16x32_bf16(Af[ks], Bf[nt][ks], a, 0, 0, 0);
            acc[mt][nt] = a;
        }
    }
    #pragma unroll
    for (int mt = 0; mt < 8; ++mt) {
        int F = (w * 8 + mt) * 16 + sub * 4;
        f32x4 bias = zz;
        if (w == 0)      bias = *(const f32x4*)(bgl + F);
        else if (w == 1) bias = *(const f32x4*)(bcl + (F - 128));
        #pragma unroll
        for (int nt = 0; nt < 2; ++nt) {
            int node = node0 + nt * 16 + rA;
            if (node >= N_NODES) continue;
            f32x4 vv = acc[mt][nt];
            vv[0] += bias[0]; vv[1] += bias[1]; vv[2] += bias[2]; vv[3] += bias[3];
            if (w < 2) {
                if constexpr (sizeof(TD) == 4) {
                    *(f32x4*)(NBd + (size_t)node * 256 + F) = vv;
                } else {
                    bf16x4 bv;
                    bv[0] = (__bf16)vv[0]; bv[1] = (__bf16)vv[1];
                    bv[2] = (__bf16)vv[2]; bv[3] = (__bf16)vv[3];
                    *(bf16x4*)((__bf16*)NBd + (size_t)node * 256 + F) = bv;
                }
            } else {
                bf16x4 bv;
                bv[0] = (__bf16)vv[0]; bv[1] = (__bf16)vv[1];
                bv[2] = (__bf16)vv[2]; bv[3] = (__bf16)vv[3];
                *(bf16x4*)(NBs + (size_t)node * 256 + (F - 256)) = bv;
            }
        }
    }
}

template <typename TD>
__device__ __forceinline__ f32x4 ld_nb4(const TD* p) {
    if constexpr (sizeof(TD) == 4) {
        return *(const f32x4*)p;
    } else {
        bf16x4 t = *(const bf16x4*)p;
        f32x4 r;
        r[0] = (float)t[0]; r[1] = (float)t[1]; r[2] = (float)t[2]; r[3] = (float)t[3];
        return r;
    }
}

// ---------------------------------------------------------------------------
// Message layer, dst-sorted, all blocks full (padded edges -> dummy node).
// EB=64: f32 mF = 32 KB, total LDS ~34 KB -> 4 blocks/CU at the body's
// natural ~52 VGPRs. NO min-waves pin (R11: pin->32 VGPR->scratch thrash).
// ---------------------------------------------------------------------------
template <typename TD>
__global__ void __launch_bounds__(512) k_msg(
    const char* __restrict__ ea2, const int* __restrict__ dstS,
    const int* __restrict__ srcS, const __bf16* __restrict__ WeT,
    const TD* __restrict__ NBd, const __bf16* __restrict__ NBs,
    float* __restrict__ h, int layer)
{
    __shared__ __align__(16) float mF[EB * 128];   // 32 KB messages (XOR-swizzled)
    __shared__ int rs[SPANMAX], re[SPANMAX];
    int tid = threadIdx.x, lane = tid & 63, w = tid >> 6;
    int sub = lane >> 4, rA = lane & 15;
    int e0 = blockIdx.x * EB;
    int F = w * 16 + sub * 4;
    int n0 = dstS[e0];

    // run-boundary tables (gap-fill by run-starter; no init barrier needed)
    if (tid < EB) {
        int d = dstS[e0 + tid];
        int di = min(d - n0, SPANMAX - 1);
        if (tid == 0 || dstS[e0 + tid - 1] != d) {
            rs[di] = tid;
            if (tid > 0) {
                int dp = dstS[e0 + tid - 1];
                for (int g = dp + 1; g < d && (g - n0) < SPANMAX; ++g) {
                    rs[g - n0] = 0; re[g - n0] = 0;
                }
            }
        }
        if (tid == EB - 1 || dstS[e0 + tid + 1] != d) re[di] = tid + 1;
    }

    // folded edge-weight A-frags (registers, L2-resident)
    bf16x8 Ag[3], Ac[3];
    {
        const __bf16* bg_ = WeT + (size_t)(((layer * 2 + 0) * 8 + w) * 3) * 512;
        const __bf16* bc_ = WeT + (size_t)(((layer * 2 + 1) * 8 + w) * 3) * 512;
        #pragma unroll
        for (int ks = 0; ks < 3; ++ks) {
            Ag[ks] = *(const bf16x8*)(bg_ + ks * 512 + lane * 8);
            Ac[ks] = *(const bf16x8*)(bc_ + ks * 512 + lane * 8);
        }
    }

    // hoisted loop-invariant bases
    const char* eb0 = ea2 + ((size_t)(0 + sub) * EP + e0 + rA) * 16;
    const char* eb1 = ea2 + ((size_t)(4 + sub) * EP + e0 + rA) * 16;
    const char* eb2 = ea2 + ((size_t)(8 + sub) * EP + e0 + rA) * 16;
    const int* srcp = srcS + e0 + rA;
    const int* dstp = dstS + e0 + rA;
    char* mfp = (char*)mF + rA * 512 + ((w * 64 + sub * 16) ^ ((rA & 7) << 4));

    f32x4 zz = {0.f, 0.f, 0.f, 0.f};
    // depth-2 pipelined register sets (indices fold to constants under unroll)
    bf16x8 bfr[2][3];
    bf16x4 gs[2], cs[2];
    f32x4  gd[2], cd[2];

    // prologue: load nt=0
    {
        int src = srcp[0], dstc = min(dstp[0], N_NODES - 1);
        bfr[0][0] = *(const bf16x8*)(eb0);
        bfr[0][1] = *(const bf16x8*)(eb1);
        bfr[0][2] = *(const bf16x8*)(eb2);
        gs[0] = *(const bf16x4*)(NBs + (size_t)src * 256 + F);
        cs[0] = *(const bf16x4*)(NBs + (size_t)src * 256 + 128 + F);
        gd[0] = ld_nb4(NBd + (size_t)dstc * 256 + F);
        cd[0] = ld_nb4(NBd + (size_t)dstc * 256 + 128 + F);
    }
    #pragma unroll
    for (int nt = 0; nt < EB / 16; ++nt) {
        int cur = nt & 1, nxt = cur ^ 1;
        if (nt + 1 < EB / 16) {   // prefetch next sub-tile
            int src = srcp[(nt + 1) * 16], dstc = min(dstp[(nt + 1) * 16], N_NODES - 1);
            bfr[nxt][0] = *(const bf16x8*)(eb0 + (nt + 1) * 256);
            bfr[nxt][1] = *(const bf16x8*)(eb1 + (nt + 1) * 256);
            bfr[nxt][2] = *(const bf16x8*)(eb2 + (nt + 1) * 256);
            gs[nxt] = *(const bf16x4*)(NBs + (size_t)src * 256 + F);
            cs[nxt] = *(const bf16x4*)(NBs + (size_t)src * 256 + 128 + F);
            gd[nxt] = ld_nb4(NBd + (size_t)dstc * 256 + F);
            cd[nxt] = ld_nb4(NBd + (size_t)dstc * 256 + 128 + F);
        }
        f32x4 aG = zz, aC = zz;
        #pragma unroll
        for (int ks = 0; ks < 3; ++ks) {
            aG = __builtin_amdgcn_mfma_f32_16x16x32_bf16(Ag[ks], bfr[cur][ks], aG, 0, 0, 0);
            aC = __builtin_amdgcn_mfma_f32_16x16x32_bf16(Ac[ks], bfr[cur][ks], aC, 0, 0, 0);
        }
        f32x4 mv;
        #pragma unroll
        for (int r = 0; r < 4; ++r) {
            float gi = aG[r] + gd[cur][r] + (float)gs[cur][r];
            float ci = aC[r] + cd[cur][r] + (float)cs[cur][r];
            mv[r] = sigmoidf_(gi) * softplusf_(ci);
        }
        *(f32x4*)(mfp + nt * 8192) = mv;
    }
    __syncthreads();
    // segment-sum over runs -> h (16B feature granularity)
    int span = min(dstS[e0 + EB - 1] - n0 + 1, SPANMAX);
    int items = span * 32;
    for (int it = tid; it < items; it += 512) {
        int ln = it >> 5, fq = it & 31;
        int rs_ = rs[ln], re_ = re[ln];
        f32x4 s = zz;
        for (int e = rs_; e < re_; ++e) {
            f32x4 v = *(const f32x4*)((char*)mF + e * 512 + ((fq * 16) ^ ((e & 7) << 4)));
            s[0] += v[0]; s[1] += v[1]; s[2] += v[2]; s[3] += v[3];
        }
        int node = n0 + ln;
        float* dp = h + (size_t)node * 128 + fq * 4;
        if (ln == 0 || ln == span - 1) {
            atomicAdd(dp + 0, s[0]); atomicAdd(dp + 1, s[1]);
            atomicAdd(dp + 2, s[2]); atomicAdd(dp + 3, s[3]);
        } else {
            dp[0] += s[0]; dp[1] += s[1]; dp[2] += s[2]; dp[3] += s[3];
        }
    }
}

// ---------------------------------------------------------------------------
// Readout
// ---------------------------------------------------------------------------
__global__ void __launch_bounds__(128) k_readout(const float* __restrict__ h,
    const int* __restrict__ batch, const float* __restrict__ W1,
    const float* __restrict__ b1, const float* __restrict__ W2,
    const float* __restrict__ b2, float* __restrict__ out) {
    int g = blockIdx.x, tid = threadIdx.x;
    __shared__ int se[2];
    __shared__ float pl[NF];
    __shared__ float red[2];
    if (tid < 2) {
        int target = g + tid;
        int lo = 0, hi = N_NODES;
        while (lo < hi) { int mid = (lo + hi) >> 1; if (batch[mid] < target) lo = mid + 1; else hi = mid; }
        se[tid] = lo;
    }
    __syncthreads();
    int s = se[0], e = se[1];
    float sum = 0.0f;
    for (int n = s; n < e; ++n) sum += h[(size_t)n * NF + tid];
    float cnt = (float)max(e - s, 1);
    pl[tid] = sum / cnt;
    __syncthreads();
    float acc = b1[tid];
    for (int c = 0; c < NF; ++c) acc += pl[c] * W1[c * NF + tid];
    float hid = siluf_(acc);
    float v = hid * W2[tid];
    #pragma unroll
    for (int off = 32; off > 0; off >>= 1) v += __shfl_down(v, off);
    if ((tid & 63) == 0) red[tid >> 6] = v;
    __syncthreads();
    if (tid == 0) out[g] = red[0] + red[1] + b2[0];
}

// ---------------------------------------------------------------------------
extern "C" void kernel_launch(void* const* d_in, const int* in_sizes, int n_in,
                              void* d_out, int out_size, void* d_ws, size_t ws_size,
                              hipStream_t stream) {
    const float* x     = (const float*)d_in[0];
    const int*   eidx  = (const int*)d_in[1];
    const float* sh    = (const float*)d_in[2];
    const float* edist = (const float*)d_in[3];
    const int*   batch = (const int*)d_in[4];
    const float* W_emb = (const float*)d_in[5];
    const float* b_emb = (const float*)d_in[6];
    const float* shW1  = (const float*)d_in[7];
    const float* shB1  = (const float*)d_in[8];
    const float* shW2  = (const float*)d_in[9];
    const float* shB2  = (const float*)d_in[10];
    const float* rbW1  = (const float*)d_in[11];
    const float* rbB1  = (const float*)d_in[12];
    const float* rbW2  = (const float*)d_in[13];
    const float* rbB2  = (const float*)d_in[14];
    const float* Wg    = (const float*)d_in[15];
    const float* bg    = (const float*)d_in[16];
    const float* Wc    = (const float*)d_in[17];
    const float* bc    = (const float*)d_in[18];
    const float* fcW1  = (const float*)d_in[19];
    const float* fcb1  = (const float*)d_in[20];
    const float* fcW2  = (const float*)d_in[21];
    const float* fcb2  = (const float*)d_in[22];
    const int* srcI = eidx;
    const int* dstI = eidx + N_EDGES;

    char* ws = (char*)d_ws;
    float*  h     = (float*)(ws + 0);              // 25,600,512 (50001 rows; last = dummy)
    char*   ea2   = (char*)(ws + 25600512);        // 96,018,432 (12 planes x EP x 16B)
    int*    dstS  = (int*)(ws + 121618944);        //  2,000,384 (EP entries)
    int*    srcS  = (int*)(ws + 123619328);        //  2,000,384
    int*    deg   = (int*)(ws + 125619712);        //    200,000
    int*    curs  = (int*)(ws + 125819712);        //    200,000
    int*    perm  = (int*)(ws + 126019712);        //  2,000,000
    __bf16* WeT   = (__bf16*)(ws + 128019712);     //    245,760
    __bf16* WnT   = (__bf16*)(ws + 128265472);     //    655,360
    float*  Wfold = (float*)(ws + 128920832);      //    491,520
    float*  bF    = (float*)(ws + 129412352);      //      5,120
    __bf16* NBs   = (__bf16*)(ws + 129417472);     // 25,600,000
    void*   NBd   = (void*)(ws + 155017472);       // 51.2 MB (f32) or 25.6 MB (bf16)
    bool nbf32 = (ws_size >= 206217472ULL);

    hipMemsetAsync(deg, 0, (size_t)N_NODES * sizeof(int), stream);
    k_fold<<<10, 256, 0, stream>>>(Wg, Wc, rbW2, rbB2, shW2, shB2, bg, bc, Wfold, bF);
    k_prep_w<<<220, 256, 0, stream>>>(Wg, Wc, Wfold, WeT, WnT);
    k_embed<<<N_NODES / 8, 256, 0, stream>>>(x, W_emb, b_emb, h);
    k_deg<<<(N_EDGES + 255) / 256, 256, 0, stream>>>(dstI, deg);
    k_scan<<<1, 1024, 0, stream>>>(deg, curs);
    k_scatter<<<(N_EDGES + 255) / 256, 256, 0, stream>>>(srcI, dstI, curs, perm, dstS, srcS);
    k_edge<<<(N_EDGES + 255) / 256, 256, 0, stream>>>(sh, edist, perm, shW1, shB1,
                                                      rbW1, rbB1, ea2);
    k_pad<<<1, 128, 0, stream>>>(dstS, srcS, ea2);
    for (int l = 0; l < N_LAYERS; ++l) {
        const float* bgF = bF + (l * 2 + 0) * 128;
        const float* bcF = bF + (l * 2 + 1) * 128;
        if (nbf32) {
            k_node<float><<<(N_NODES + 31) / 32, 256, 0, stream>>>(
                h, WnT, bgF, bcF, (float*)NBd, NBs, l);
            k_msg<float><<<EP / EB, 512, 0, stream>>>(
                ea2, dstS, srcS, WeT, (const float*)NBd, NBs, h, l);
        } else {
            k_node<__bf16><<<(N_NODES + 31) / 32, 256, 0, stream>>>(
                h, WnT, bgF, bcF, (__bf16*)NBd, NBs, l);
            k_msg<__bf16><<<EP / EB, 512, 0, stream>>>(
                ea2, dstS, srcS, WeT, (const __bf16*)NBd, NBs, h, l);
        }
    }
    k_readout<<<N_GRAPHS, 128, 0, stream>>>(h, batch, fcW1, fcb1, fcW2, fcb2, (float*)d_out);
}

// Round 13
// 1187.239 us; speedup vs baseline: 1.4476x; 1.1071x over previous
//
#include <hip/hip_runtime.h>

typedef __bf16 bf16x8 __attribute__((ext_vector_type(8)));
typedef __bf16 bf16x4 __attribute__((ext_vector_type(4)));
typedef float  f32x4  __attribute__((ext_vector_type(4)));

#define N_NODES  50000
#define N_EDGES  500000
#define EB       128         // edges per k_msg block
#define EP       500096      // padded edge count (multiple of EB)
#define NCH      12          // 16B chunks per edge row (96 bf16)
#define N_GRAPHS 1024
#define NF       128
#define IN_DIM   92
#define N_LAYERS 5
#define SPANMAX  256

__device__ __forceinline__ float sigmoidf_(float x) { return 1.0f / (1.0f + __expf(-x)); }
__device__ __forceinline__ float softplusf_(float x) {
    return fmaxf(x, 0.0f) + __logf(1.0f + __expf(-fabsf(x)));
}
__device__ __forceinline__ float siluf_(float x) { return x * sigmoidf_(x); }

// ---------------------------------------------------------------------------
// Fold the edge-MLP second stage into layer weights (see R6 notes).
// ---------------------------------------------------------------------------
__global__ void __launch_bounds__(256) k_fold(const float* __restrict__ Wg,
    const float* __restrict__ Wc, const float* __restrict__ rbW2,
    const float* __restrict__ rbB2, const float* __restrict__ shW2,
    const float* __restrict__ shB2, const float* __restrict__ bg,
    const float* __restrict__ bc, float* __restrict__ Wfold,
    float* __restrict__ bF) {
    int lg = blockIdx.x, l = lg >> 1, g = lg & 1;
    const float* W = (g ? Wc : Wg) + (size_t)l * 384 * 128;
    const float* bsrc = (g ? bc : bg) + l * 128;
    int tid = threadIdx.x;
    for (int idx = tid; idx < 96 * 128; idx += 256) {
        int r = idx >> 7, n = idx & 127;
        float s = 0.f;
        if (r < 64) {
            for (int o = 0; o < 64; ++o) s += rbW2[r * 64 + o] * W[(256 + o) * 128 + n];
        } else {
            int j = r - 64;
            for (int o = 0; o < 64; ++o) s += shW2[j * 64 + o] * W[(320 + o) * 128 + n];
        }
        Wfold[(size_t)lg * 12288 + idx] = s;
    }
    if (tid < 128) {
        float s = bsrc[tid];
        for (int o = 0; o < 64; ++o) s += rbB2[o] * W[(256 + o) * 128 + tid];
        for (int o = 0; o < 64; ++o) s += shB2[o] * W[(320 + o) * 128 + tid];
        bF[lg * 128 + tid] = s;
    }
}

// ---------------------------------------------------------------------------
// Weight prep: WeT = A-frags of Wfold^T; WnT = A-frags of node weights.
// ---------------------------------------------------------------------------
__global__ void __launch_bounds__(256) k_prep_w(const float* __restrict__ Wg,
                                                const float* __restrict__ Wc,
                                                const float* __restrict__ Wfold,
                                                __bf16* __restrict__ WeT,
                                                __bf16* __restrict__ WnT) {
    int t = blockIdx.x * 256 + threadIdx.x;
    if (t >= (240 + 640) * 64) return;
    int frag = t >> 6, lane = t & 63;
    int sub = lane >> 4, mm = lane & 15;
    bf16x8 v;
    if (frag < 240) {
        int lg = frag / 24; int r = frag % 24;
        int m = r / 3; int ks = r % 3;
        #pragma unroll
        for (int j = 0; j < 8; ++j) {
            int k = ks * 32 + sub * 8 + j;
            v[j] = (__bf16)Wfold[(size_t)lg * 12288 + (size_t)k * 128 + m * 16 + mm];
        }
        *(bf16x8*)(WeT + (size_t)frag * 512 + lane * 8) = v;
    } else {
        int f2 = frag - 240;
        int l = f2 / 128; int r = f2 % 128;
        int m = r >> 2; int ks = r & 3;
        int F = m * 16 + mm;
        #pragma unroll
        for (int j = 0; j < 8; ++j) {
            int k = ks * 32 + sub * 8 + j;
            float val;
            if      (F < 128) val = Wg[(size_t)l*384*128 + (size_t)k*128 + F];
            else if (F < 256) val = Wc[(size_t)l*384*128 + (size_t)k*128 + (F-128)];
            else if (F < 384) val = Wg[(size_t)l*384*128 + (size_t)(128+k)*128 + (F-256)];
            else              val = Wc[(size_t)l*384*128 + (size_t)(128+k)*128 + (F-384)];
            v[j] = (__bf16)val;
        }
        *(bf16x8*)(WnT + (size_t)f2 * 512 + lane * 8) = v;
    }
}

// ---------------------------------------------------------------------------
// CSR build
// ---------------------------------------------------------------------------
__global__ void __launch_bounds__(256) k_deg(const int* __restrict__ dstI,
                                             int* __restrict__ deg) {
    int e = blockIdx.x * 256 + threadIdx.x;
    if (e < N_EDGES) atomicAdd(&deg[dstI[e]], 1);
}

__global__ void __launch_bounds__(1024) k_scan(const int* __restrict__ deg,
                                               int* __restrict__ cursor) {
    __shared__ int ps[1024];
    int t = threadIdx.x;
    const int C = (N_NODES + 1023) / 1024;
    int base = t * C;
    int s = 0;
    for (int i = 0; i < C; ++i) { int idx = base + i; if (idx < N_NODES) s += deg[idx]; }
    ps[t] = s;
    __syncthreads();
    for (int off = 1; off < 1024; off <<= 1) {
        int v = 0;
        if (t >= off) v = ps[t - off];
        __syncthreads();
        if (t >= off) ps[t] += v;
        __syncthreads();
    }
    int run = (t > 0) ? ps[t - 1] : 0;
    for (int i = 0; i < C; ++i) {
        int idx = base + i;
        if (idx < N_NODES) { cursor[idx] = run; run += deg[idx]; }
    }
}

__global__ void __launch_bounds__(256) k_scatter(const int* __restrict__ srcI,
                                                 const int* __restrict__ dstI,
                                                 int* __restrict__ cursor,
                                                 int* __restrict__ perm,
                                                 int* __restrict__ dstS,
                                                 int2* __restrict__ sdS) {
    int e = blockIdx.x * 256 + threadIdx.x;
    if (e >= N_EDGES) return;
    int d = dstI[e];
    int p = atomicAdd(&cursor[d], 1);
    perm[p] = e;
    dstS[p] = d;
    sdS[p] = make_int2(d, srcI[e]);
}

// ---------------------------------------------------------------------------
// Pad entries [N_EDGES, EP): dummy dst node N_NODES, src 0, zeroed ea2 chunks.
// ---------------------------------------------------------------------------
__global__ void __launch_bounds__(128) k_pad(int* __restrict__ dstS,
                                             int2* __restrict__ sdS,
                                             char* __restrict__ ea2) {
    int i = threadIdx.x;
    if (i < EP - N_EDGES) {
        dstS[N_EDGES + i] = N_NODES;
        sdS[N_EDGES + i] = make_int2(N_NODES, 0);
        uint4 z = {0, 0, 0, 0};
        for (int p = 0; p < NCH; ++p)
            *(uint4*)(ea2 + ((size_t)p * EP + N_EDGES + i) * 16) = z;
    }
}

// ---------------------------------------------------------------------------
// Atom embedding: h = x @ W_emb + b_emb (f32)
// ---------------------------------------------------------------------------
__global__ void __launch_bounds__(256) k_embed(const float* __restrict__ x,
                                               const float* __restrict__ W,
                                               const float* __restrict__ b,
                                               float* __restrict__ h) {
    int tid = threadIdx.x;
    int f = tid & 127;
    int nb = blockIdx.x * 8 + (tid >> 7) * 4;   // 8 nodes per block
    const float* x0 = x + (size_t)nb * IN_DIM;
    float a0 = b[f], a1 = a0, a2 = a0, a3 = a0;
    #pragma unroll 4
    for (int k = 0; k < IN_DIM; ++k) {
        float wv = W[k * NF + f];
        a0 = fmaf(x0[k], wv, a0);
        a1 = fmaf(x0[IN_DIM + k], wv, a1);
        a2 = fmaf(x0[2 * IN_DIM + k], wv, a2);
        a3 = fmaf(x0[3 * IN_DIM + k], wv, a3);
    }
    float accs[4] = {a0, a1, a2, a3};
    #pragma unroll
    for (int r = 0; r < 4; ++r)
        h[(size_t)(nb + r) * NF + f] = accs[r];
}

// ---------------------------------------------------------------------------
// Edge hidden features eh[e][96], dst-sorted, transposed chunk-plane layout.
// ---------------------------------------------------------------------------
__global__ void __launch_bounds__(256) k_edge(const float* __restrict__ sh,
    const float* __restrict__ dist, const int* __restrict__ perm,
    const float* __restrict__ shW1, const float* __restrict__ shB1,
    const float* __restrict__ rbW1, const float* __restrict__ rbB1,
    char* __restrict__ ea2) {
    __shared__ float wf[4480];
    int tid = threadIdx.x;
    int p = blockIdx.x * 256 + tid;
    bool pv = p < N_EDGES;
    int e = pv ? perm[p] : 0;
    float dv = dist[e];
    float shv[9];
    #pragma unroll
    for (int i = 0; i < 9; ++i) shv[i] = sh[(size_t)e * 9 + i];
    for (int i = tid; i < 288;  i += 256) wf[i]        = shW1[i];
    for (int i = tid; i < 32;   i += 256) wf[288 + i]  = shB1[i];
    for (int i = tid; i < 4096; i += 256) wf[320 + i]  = rbW1[i];
    for (int i = tid; i < 64;   i += 256) wf[4416 + i] = rbB1[i];
    __syncthreads();
    if (!pv) return;

    const float* W1 = wf + 320; const float* B1 = wf + 4416;
    float invd = 1.0f / dv;
    const float step = (1.4f - 0.125f) / 63.0f;
    const float gam = 1.0f / (step * step);
    float hid[64];
    #pragma unroll
    for (int j = 0; j < 64; ++j) hid[j] = B1[j];
    for (int i = 0; i < 64; ++i) {
        float c = 0.125f + i * step;
        float d = invd - c;
        float r = __expf(-gam * d * d);
        #pragma unroll
        for (int j = 0; j < 64; ++j) hid[j] += r * W1[i * 64 + j];
    }
    #pragma unroll
    for (int o8 = 0; o8 < 8; ++o8) {
        bf16x8 v;
        #pragma unroll
        for (int j = 0; j < 8; ++j) v[j] = (__bf16)siluf_(hid[o8 * 8 + j]);
        *(bf16x8*)(ea2 + ((size_t)o8 * EP + p) * 16) = v;
    }
    const float* sW1 = wf; const float* sB1 = wf + 288;
    float h2[32];
    #pragma unroll
    for (int j = 0; j < 32; ++j) h2[j] = sB1[j];
    #pragma unroll
    for (int i = 0; i < 9; ++i) {
        float si = shv[i];
        #pragma unroll
        for (int j = 0; j < 32; ++j) h2[j] += si * sW1[i * 32 + j];
    }
    #pragma unroll
    for (int o8 = 0; o8 < 4; ++o8) {
        bf16x8 v;
        #pragma unroll
        for (int j = 0; j < 8; ++j) v[j] = (__bf16)siluf_(h2[o8 * 8 + j]);
        *(bf16x8*)(ea2 + ((size_t)(8 + o8) * EP + p) * 16) = v;
    }
}

// ---------------------------------------------------------------------------
// Per-node GEMM -> unified interleaved bf16 buffer:
// NB2[node][fq][16] = [gd(4) | cd(4) | gs(4) | cs(4)], fq = F-group 0..31.
// One bf16x8 load serves {gd,cd} (dst side); one serves {gs,cs} (src side).
// ---------------------------------------------------------------------------
__global__ void __launch_bounds__(256) k_node(const float* __restrict__ h,
                                              const __bf16* __restrict__ WnT,
                                              const float* __restrict__ bgl,
                                              const float* __restrict__ bcl,
                                              __bf16* __restrict__ NB2, int layer) {
    int tid = threadIdx.x, lane = tid & 63, w = tid >> 6;
    int sub = lane >> 4, rA = lane & 15;
    int node0 = blockIdx.x * 32;
    bf16x8 Bf[2][4];
    #pragma unroll
    for (int nt = 0; nt < 2; ++nt)
        #pragma unroll
        for (int ks = 0; ks < 4; ++ks) {
            int node = min(node0 + nt * 16 + rA, N_NODES - 1);
            const float* hr = h + (size_t)node * 128 + ks * 32 + sub * 8;
            f32x4 u0 = *(const f32x4*)hr;
            f32x4 u1 = *(const f32x4*)(hr + 4);
            bf16x8 bv;
            bv[0] = (__bf16)u0[0]; bv[1] = (__bf16)u0[1];
            bv[2] = (__bf16)u0[2]; bv[3] = (__bf16)u0[3];
            bv[4] = (__bf16)u1[0]; bv[5] = (__bf16)u1[1];
            bv[6] = (__bf16)u1[2]; bv[7] = (__bf16)u1[3];
            Bf[nt][ks] = bv;
        }
    const __bf16* Wbase = WnT + (size_t)layer * 128 * 512;
    f32x4 acc[8][2];
    f32x4 zz = {0.f, 0.f, 0.f, 0.f};
    #pragma unroll
    for (int mt = 0; mt < 8; ++mt) { acc[mt][0] = zz; acc[mt][1] = zz; }
    for (int mt = 0; mt < 8; ++mt) {
        int gm = w * 8 + mt;
        bf16x8 Af[4];
        #pragma unroll
        for (int ks = 0; ks < 4; ++ks)
            Af[ks] = *(const bf16x8*)(Wbase + (size_t)(gm * 4 + ks) * 512 + lane * 8);
        #pragma unroll
        for (int nt = 0; nt < 2; ++nt) {
            f32x4 a = acc[mt][nt];
            #pragma unroll
            for (int ks = 0; ks < 4; ++ks)
                a = __builtin_amdgcn_mfma_f32_16x16x32_bf16(Af[ks], Bf[nt][ks], a, 0, 0, 0);
            acc[mt][nt] = a;
        }
    }
    #pragma unroll
    for (int mt = 0; mt < 8; ++mt) {
        int F = (w * 8 + mt) * 16 + sub * 4;     // global feature 0..511
        int part = F >> 7;                       // 0=gd 1=cd 2=gs 3=cs
        int fq = (F & 127) >> 2;                 // F-group 0..31
        f32x4 bias = zz;
        if (part == 0)      bias = *(const f32x4*)(bgl + (F & 127));
        else if (part == 1) bias = *(const f32x4*)(bcl + (F & 127));
        #pragma unroll
        for (int nt = 0; nt < 2; ++nt) {
            int node = node0 + nt * 16 + rA;
            if (node >= N_NODES) continue;
            f32x4 vv = acc[mt][nt];
            vv[0] += bias[0]; vv[1] += bias[1]; vv[2] += bias[2]; vv[3] += bias[3];
            bf16x4 bv;
            bv[0] = (__bf16)vv[0]; bv[1] = (__bf16)vv[1];
            bv[2] = (__bf16)vv[2]; bv[3] = (__bf16)vv[3];
            *(bf16x4*)(NB2 + (size_t)node * 512 + fq * 16 + part * 4) = bv;
        }
    }
}

// ---------------------------------------------------------------------------
// Message layer, dst-sorted, all blocks full (padded edges -> dummy node).
// Per nt per thread: 3 bfr + 1 dst-NB + 1 src-NB (bf16x8) + 1 int2 idx load.
// ---------------------------------------------------------------------------
__global__ void __launch_bounds__(512) k_msg(
    const char* __restrict__ ea2, const int* __restrict__ dstS,
    const int2* __restrict__ sdS, const __bf16* __restrict__ WeT,
    const __bf16* __restrict__ NB2, float* __restrict__ h, int layer)
{
    __shared__ __align__(16) float mF[EB * 128];   // 64 KB messages (XOR-swizzled)
    __shared__ int rs[SPANMAX], re[SPANMAX];
    int tid = threadIdx.x, lane = tid & 63, w = tid >> 6;
    int sub = lane >> 4, rA = lane & 15;
    int e0 = blockIdx.x * EB;
    int fq = w * 4 + sub;                          // F-group 0..31
    int n0 = dstS[e0];

    // run-boundary tables (gap-fill by run-starter; no init barrier needed)
    if (tid < EB) {
        int d = dstS[e0 + tid];
        int di = min(d - n0, SPANMAX - 1);
        if (tid == 0 || dstS[e0 + tid - 1] != d) {
            rs[di] = tid;
            if (tid > 0) {
                int dp = dstS[e0 + tid - 1];
                for (int g = dp + 1; g < d && (g - n0) < SPANMAX; ++g) {
                    rs[g - n0] = 0; re[g - n0] = 0;
                }
            }
        }
        if (tid == EB - 1 || dstS[e0 + tid + 1] != d) re[di] = tid + 1;
    }

    // folded edge-weight A-frags (registers, L2-resident)
    bf16x8 Ag[3], Ac[3];
    {
        const __bf16* bg_ = WeT + (size_t)(((layer * 2 + 0) * 8 + w) * 3) * 512;
        const __bf16* bc_ = WeT + (size_t)(((layer * 2 + 1) * 8 + w) * 3) * 512;
        #pragma unroll
        for (int ks = 0; ks < 3; ++ks) {
            Ag[ks] = *(const bf16x8*)(bg_ + ks * 512 + lane * 8);
            Ac[ks] = *(const bf16x8*)(bc_ + ks * 512 + lane * 8);
        }
    }

    // hoisted loop-invariant bases
    const char* eb0 = ea2 + ((size_t)(0 + sub) * EP + e0 + rA) * 16;
    const char* eb1 = ea2 + ((size_t)(4 + sub) * EP + e0 + rA) * 16;
    const char* eb2 = ea2 + ((size_t)(8 + sub) * EP + e0 + rA) * 16;
    const int2* sdp = sdS + e0 + rA;
    char* mfp = (char*)mF + rA * 512 + ((w * 64 + sub * 16) ^ ((rA & 7) << 4));

    f32x4 zz = {0.f, 0.f, 0.f, 0.f};
    // depth-2 pipelined register sets (indices fold to constants under unroll)
    bf16x8 bfr[2][3];
    bf16x8 dv[2], sv[2];

    // prologue: load nt=0
    {
        int2 sd = sdp[0];
        int dstc = min(sd.x, N_NODES - 1);
        bfr[0][0] = *(const bf16x8*)(eb0);
        bfr[0][1] = *(const bf16x8*)(eb1);
        bfr[0][2] = *(const bf16x8*)(eb2);
        dv[0] = *(const bf16x8*)(NB2 + (size_t)dstc * 512 + fq * 16);
        sv[0] = *(const bf16x8*)(NB2 + (size_t)sd.y * 512 + fq * 16 + 8);
    }
    #pragma unroll
    for (int nt = 0; nt < EB / 16; ++nt) {
        int cur = nt & 1, nxt = cur ^ 1;
        if (nt + 1 < EB / 16) {   // prefetch next sub-tile
            int2 sd = sdp[(nt + 1) * 16];
            int dstc = min(sd.x, N_NODES - 1);
            bfr[nxt][0] = *(const bf16x8*)(eb0 + (nt + 1) * 256);
            bfr[nxt][1] = *(const bf16x8*)(eb1 + (nt + 1) * 256);
            bfr[nxt][2] = *(const bf16x8*)(eb2 + (nt + 1) * 256);
            dv[nxt] = *(const bf16x8*)(NB2 + (size_t)dstc * 512 + fq * 16);
            sv[nxt] = *(const bf16x8*)(NB2 + (size_t)sd.y * 512 + fq * 16 + 8);
        }
        f32x4 aG = zz, aC = zz;
        #pragma unroll
        for (int ks = 0; ks < 3; ++ks) {
            aG = __builtin_amdgcn_mfma_f32_16x16x32_bf16(Ag[ks], bfr[cur][ks], aG, 0, 0, 0);
            aC = __builtin_amdgcn_mfma_f32_16x16x32_bf16(Ac[ks], bfr[cur][ks], aC, 0, 0, 0);
        }
        f32x4 mv;
        #pragma unroll
        for (int r = 0; r < 4; ++r) {
            float gi = aG[r] + (float)dv[cur][r] + (float)sv[cur][r];
            float ci = aC[r] + (float)dv[cur][4 + r] + (float)sv[cur][4 + r];
            mv[r] = sigmoidf_(gi) * softplusf_(ci);
        }
        *(f32x4*)(mfp + nt * 8192) = mv;
    }
    __syncthreads();
    // segment-sum over runs -> h (16B feature granularity)
    int span = min(dstS[e0 + EB - 1] - n0 + 1, SPANMAX);
    int items = span * 32;
    for (int it = tid; it < items; it += 512) {
        int ln = it >> 5, fqq = it & 31;
        int rs_ = rs[ln], re_ = re[ln];
        f32x4 s = zz;
        for (int e = rs_; e < re_; ++e) {
            f32x4 v = *(const f32x4*)((char*)mF + e * 512 + ((fqq * 16) ^ ((e & 7) << 4)));
            s[0] += v[0]; s[1] += v[1]; s[2] += v[2]; s[3] += v[3];
        }
        int node = n0 + ln;
        float* dp = h + (size_t)node * 128 + fqq * 4;
        if (ln == 0 || ln == span - 1) {
            atomicAdd(dp + 0, s[0]); atomicAdd(dp + 1, s[1]);
            atomicAdd(dp + 2, s[2]); atomicAdd(dp + 3, s[3]);
        } else {
            dp[0] += s[0]; dp[1] += s[1]; dp[2] += s[2]; dp[3] += s[3];
        }
    }
}

// ---------------------------------------------------------------------------
// Readout
// ---------------------------------------------------------------------------
__global__ void __launch_bounds__(128) k_readout(const float* __restrict__ h,
    const int* __restrict__ batch, const float* __restrict__ W1,
    const float* __restrict__ b1, const float* __restrict__ W2,
    const float* __restrict__ b2, float* __restrict__ out) {
    int g = blockIdx.x, tid = threadIdx.x;
    __shared__ int se[2];
    __shared__ float pl[NF];
    __shared__ float red[2];
    if (tid < 2) {
        int target = g + tid;
        int lo = 0, hi = N_NODES;
        while (lo < hi) { int mid = (lo + hi) >> 1; if (batch[mid] < target) lo = mid + 1; else hi = mid; }
        se[tid] = lo;
    }
    __syncthreads();
    int s = se[0], e = se[1];
    float sum = 0.0f;
    for (int n = s; n < e; ++n) sum += h[(size_t)n * NF + tid];
    float cnt = (float)max(e - s, 1);
    pl[tid] = sum / cnt;
    __syncthreads();
    float acc = b1[tid];
    for (int c = 0; c < NF; ++c) acc += pl[c] * W1[c * NF + tid];
    float hid = siluf_(acc);
    float v = hid * W2[tid];
    #pragma unroll
    for (int off = 32; off > 0; off >>= 1) v += __shfl_down(v, off);
    if ((tid & 63) == 0) red[tid >> 6] = v;
    __syncthreads();
    if (tid == 0) out[g] = red[0] + red[1] + b2[0];
}

// ---------------------------------------------------------------------------
extern "C" void kernel_launch(void* const* d_in, const int* in_sizes, int n_in,
                              void* d_out, int out_size, void* d_ws, size_t ws_size,
                              hipStream_t stream) {
    const float* x     = (const float*)d_in[0];
    const int*   eidx  = (const int*)d_in[1];
    const float* sh    = (const float*)d_in[2];
    const float* edist = (const float*)d_in[3];
    const int*   batch = (const int*)d_in[4];
    const float* W_emb = (const float*)d_in[5];
    const float* b_emb = (const float*)d_in[6];
    const float* shW1  = (const float*)d_in[7];
    const float* shB1  = (const float*)d_in[8];
    const float* shW2  = (const float*)d_in[9];
    const float* shB2  = (const float*)d_in[10];
    const float* rbW1  = (const float*)d_in[11];
    const float* rbB1  = (const float*)d_in[12];
    const float* rbW2  = (const float*)d_in[13];
    const float* rbB2  = (const float*)d_in[14];
    const float* Wg    = (const float*)d_in[15];
    const float* bg    = (const float*)d_in[16];
    const float* Wc    = (const float*)d_in[17];
    const float* bc    = (const float*)d_in[18];
    const float* fcW1  = (const float*)d_in[19];
    const float* fcb1  = (const float*)d_in[20];
    const float* fcW2  = (const float*)d_in[21];
    const float* fcb2  = (const float*)d_in[22];
    const int* srcI = eidx;
    const int* dstI = eidx + N_EDGES;

    char* ws = (char*)d_ws;
    float*  h     = (float*)(ws + 0);              // 25,600,512 (50001 rows; last = dummy)
    char*   ea2   = (char*)(ws + 25600512);        // 96,018,432 (12 planes x EP x 16B)
    int*    dstS  = (int*)(ws + 121618944);        //  2,000,384 (EP entries)
    int2*   sdS   = (int2*)(ws + 123619328);       //  4,000,768 (EP entries)
    int*    deg   = (int*)(ws + 127620096);        //    200,000
    int*    curs  = (int*)(ws + 127820096);        //    200,000
    int*    perm  = (int*)(ws + 128020096);        //  2,000,000
    __bf16* WeT   = (__bf16*)(ws + 130020096);     //    245,760
    __bf16* WnT   = (__bf16*)(ws + 130265856);     //    655,360
    float*  Wfold = (float*)(ws + 130921216);      //    491,520
    float*  bF    = (float*)(ws + 131412736);      //      5,120
    __bf16* NB2   = (__bf16*)(ws + 131417856);     // 51,200,000  -> ends 182.6 MB

    hipMemsetAsync(deg, 0, (size_t)N_NODES * sizeof(int), stream);
    k_fold<<<10, 256, 0, stream>>>(Wg, Wc, rbW2, rbB2, shW2, shB2, bg, bc, Wfold, bF);
    k_prep_w<<<220, 256, 0, stream>>>(Wg, Wc, Wfold, WeT, WnT);
    k_embed<<<N_NODES / 8, 256, 0, stream>>>(x, W_emb, b_emb, h);
    k_deg<<<(N_EDGES + 255) / 256, 256, 0, stream>>>(dstI, deg);
    k_scan<<<1, 1024, 0, stream>>>(deg, curs);
    k_scatter<<<(N_EDGES + 255) / 256, 256, 0, stream>>>(srcI, dstI, curs, perm, dstS, sdS);
    k_edge<<<(N_EDGES + 255) / 256, 256, 0, stream>>>(sh, edist, perm, shW1, shB1,
                                                      rbW1, rbB1, ea2);
    k_pad<<<1, 128, 0, stream>>>(dstS, sdS, ea2);
    for (int l = 0; l < N_LAYERS; ++l) {
        const float* bgF = bF + (l * 2 + 0) * 128;
        const float* bcF = bF + (l * 2 + 1) * 128;
        k_node<<<(N_NODES + 31) / 32, 256, 0, stream>>>(h, WnT, bgF, bcF, NB2, l);
        k_msg<<<EP / EB, 512, 0, stream>>>(ea2, dstS, sdS, WeT, NB2, h, l);
    }
    k_readout<<<N_GRAPHS, 128, 0, stream>>>(h, batch, fcW1, fcb1, fcW2, fcb2, (float*)d_out);
}

// Round 14
// 1158.051 us; speedup vs baseline: 1.4840x; 1.0252x over previous
//
#include <hip/hip_runtime.h>

typedef __bf16 bf16x8 __attribute__((ext_vector_type(8)));
typedef __bf16 bf16x4 __attribute__((ext_vector_type(4)));
typedef float  f32x4  __attribute__((ext_vector_type(4)));

#define N_NODES  50000
#define N_EDGES  500000
#define EB       128         // edges per k_msg block
#define EP       500096      // padded edge count (multiple of EB)
#define NCH      12          // 16B chunks per edge row (96 bf16)
#define N_GRAPHS 1024
#define NF       128
#define IN_DIM   92
#define N_LAYERS 5
#define SPANMAX  256

__device__ __forceinline__ float sigmoidf_(float x) { return 1.0f / (1.0f + __expf(-x)); }
__device__ __forceinline__ float softplusf_(float x) {
    return fmaxf(x, 0.0f) + __logf(1.0f + __expf(-fabsf(x)));
}
__device__ __forceinline__ float siluf_(float x) { return x * sigmoidf_(x); }

// ---------------------------------------------------------------------------
// Fold the edge-MLP second stage into layer weights (see R6 notes).
// ---------------------------------------------------------------------------
__global__ void __launch_bounds__(256) k_fold(const float* __restrict__ Wg,
    const float* __restrict__ Wc, const float* __restrict__ rbW2,
    const float* __restrict__ rbB2, const float* __restrict__ shW2,
    const float* __restrict__ shB2, const float* __restrict__ bg,
    const float* __restrict__ bc, float* __restrict__ Wfold,
    float* __restrict__ bF) {
    int lg = blockIdx.x, l = lg >> 1, g = lg & 1;
    const float* W = (g ? Wc : Wg) + (size_t)l * 384 * 128;
    const float* bsrc = (g ? bc : bg) + l * 128;
    int tid = threadIdx.x;
    for (int idx = tid; idx < 96 * 128; idx += 256) {
        int r = idx >> 7, n = idx & 127;
        float s = 0.f;
        if (r < 64) {
            for (int o = 0; o < 64; ++o) s += rbW2[r * 64 + o] * W[(256 + o) * 128 + n];
        } else {
            int j = r - 64;
            for (int o = 0; o < 64; ++o) s += shW2[j * 64 + o] * W[(320 + o) * 128 + n];
        }
        Wfold[(size_t)lg * 12288 + idx] = s;
    }
    if (tid < 128) {
        float s = bsrc[tid];
        for (int o = 0; o < 64; ++o) s += rbB2[o] * W[(256 + o) * 128 + tid];
        for (int o = 0; o < 64; ++o) s += shB2[o] * W[(320 + o) * 128 + tid];
        bF[lg * 128 + tid] = s;
    }
}

// ---------------------------------------------------------------------------
// Weight prep: WeT = A-frags of Wfold^T; WnT = A-frags of node weights.
// ---------------------------------------------------------------------------
__global__ void __launch_bounds__(256) k_prep_w(const float* __restrict__ Wg,
                                                const float* __restrict__ Wc,
                                                const float* __restrict__ Wfold,
                                                __bf16* __restrict__ WeT,
                                                __bf16* __restrict__ WnT) {
    int t = blockIdx.x * 256 + threadIdx.x;
    if (t >= (240 + 640) * 64) return;
    int frag = t >> 6, lane = t & 63;
    int sub = lane >> 4, mm = lane & 15;
    bf16x8 v;
    if (frag < 240) {
        int lg = frag / 24; int r = frag % 24;
        int m = r / 3; int ks = r % 3;
        #pragma unroll
        for (int j = 0; j < 8; ++j) {
            int k = ks * 32 + sub * 8 + j;
            v[j] = (__bf16)Wfold[(size_t)lg * 12288 + (size_t)k * 128 + m * 16 + mm];
        }
        *(bf16x8*)(WeT + (size_t)frag * 512 + lane * 8) = v;
    } else {
        int f2 = frag - 240;
        int l = f2 / 128; int r = f2 % 128;
        int m = r >> 2; int ks = r & 3;
        int F = m * 16 + mm;
        #pragma unroll
        for (int j = 0; j < 8; ++j) {
            int k = ks * 32 + sub * 8 + j;
            float val;
            if      (F < 128) val = Wg[(size_t)l*384*128 + (size_t)k*128 + F];
            else if (F < 256) val = Wc[(size_t)l*384*128 + (size_t)k*128 + (F-128)];
            else if (F < 384) val = Wg[(size_t)l*384*128 + (size_t)(128+k)*128 + (F-256)];
            else              val = Wc[(size_t)l*384*128 + (size_t)(128+k)*128 + (F-384)];
            v[j] = (__bf16)val;
        }
        *(bf16x8*)(WnT + (size_t)f2 * 512 + lane * 8) = v;
    }
}

// ---------------------------------------------------------------------------
// CSR build
// ---------------------------------------------------------------------------
__global__ void __launch_bounds__(256) k_deg(const int* __restrict__ dstI,
                                             int* __restrict__ deg) {
    int e = blockIdx.x * 256 + threadIdx.x;
    if (e < N_EDGES) atomicAdd(&deg[dstI[e]], 1);
}

__global__ void __launch_bounds__(1024) k_scan(const int* __restrict__ deg,
                                               int* __restrict__ cursor) {
    __shared__ int ps[1024];
    int t = threadIdx.x;
    const int C = (N_NODES + 1023) / 1024;
    int base = t * C;
    int s = 0;
    for (int i = 0; i < C; ++i) { int idx = base + i; if (idx < N_NODES) s += deg[idx]; }
    ps[t] = s;
    __syncthreads();
    for (int off = 1; off < 1024; off <<= 1) {
        int v = 0;
        if (t >= off) v = ps[t - off];
        __syncthreads();
        if (t >= off) ps[t] += v;
        __syncthreads();
    }
    int run = (t > 0) ? ps[t - 1] : 0;
    for (int i = 0; i < C; ++i) {
        int idx = base + i;
        if (idx < N_NODES) { cursor[idx] = run; run += deg[idx]; }
    }
}

__global__ void __launch_bounds__(256) k_scatter(const int* __restrict__ srcI,
                                                 const int* __restrict__ dstI,
                                                 int* __restrict__ cursor,
                                                 int* __restrict__ perm,
                                                 int* __restrict__ dstS,
                                                 int2* __restrict__ sdS) {
    int e = blockIdx.x * 256 + threadIdx.x;
    if (e >= N_EDGES) return;
    int d = dstI[e];
    int p = atomicAdd(&cursor[d], 1);
    perm[p] = e;
    dstS[p] = d;
    sdS[p] = make_int2(d, srcI[e]);
}

// ---------------------------------------------------------------------------
// Pad entries [N_EDGES, EP): dummy dst node N_NODES, src 0, zeroed ea2 chunks.
// ---------------------------------------------------------------------------
__global__ void __launch_bounds__(128) k_pad(int* __restrict__ dstS,
                                             int2* __restrict__ sdS,
                                             char* __restrict__ ea2) {
    int i = threadIdx.x;
    if (i < EP - N_EDGES) {
        dstS[N_EDGES + i] = N_NODES;
        sdS[N_EDGES + i] = make_int2(N_NODES, 0);
        uint4 z = {0, 0, 0, 0};
        for (int p = 0; p < NCH; ++p)
            *(uint4*)(ea2 + ((size_t)p * EP + N_EDGES + i) * 16) = z;
    }
}

// ---------------------------------------------------------------------------
// Atom embedding: h = x @ W_emb + b_emb (f32)
// ---------------------------------------------------------------------------
__global__ void __launch_bounds__(256) k_embed(const float* __restrict__ x,
                                               const float* __restrict__ W,
                                               const float* __restrict__ b,
                                               float* __restrict__ h) {
    int tid = threadIdx.x;
    int f = tid & 127;
    int nb = blockIdx.x * 8 + (tid >> 7) * 4;   // 8 nodes per block
    const float* x0 = x + (size_t)nb * IN_DIM;
    float a0 = b[f], a1 = a0, a2 = a0, a3 = a0;
    #pragma unroll 4
    for (int k = 0; k < IN_DIM; ++k) {
        float wv = W[k * NF + f];
        a0 = fmaf(x0[k], wv, a0);
        a1 = fmaf(x0[IN_DIM + k], wv, a1);
        a2 = fmaf(x0[2 * IN_DIM + k], wv, a2);
        a3 = fmaf(x0[3 * IN_DIM + k], wv, a3);
    }
    float accs[4] = {a0, a1, a2, a3};
    #pragma unroll
    for (int r = 0; r < 4; ++r)
        h[(size_t)(nb + r) * NF + f] = accs[r];
}

// ---------------------------------------------------------------------------
// Edge hidden features eh[e][96], dst-sorted, transposed chunk-plane layout.
// ---------------------------------------------------------------------------
__global__ void __launch_bounds__(256) k_edge(const float* __restrict__ sh,
    const float* __restrict__ dist, const int* __restrict__ perm,
    const float* __restrict__ shW1, const float* __restrict__ shB1,
    const float* __restrict__ rbW1, const float* __restrict__ rbB1,
    char* __restrict__ ea2) {
    __shared__ float wf[4480];
    int tid = threadIdx.x;
    int p = blockIdx.x * 256 + tid;
    bool pv = p < N_EDGES;
    int e = pv ? perm[p] : 0;
    float dv = dist[e];
    float shv[9];
    #pragma unroll
    for (int i = 0; i < 9; ++i) shv[i] = sh[(size_t)e * 9 + i];
    for (int i = tid; i < 288;  i += 256) wf[i]        = shW1[i];
    for (int i = tid; i < 32;   i += 256) wf[288 + i]  = shB1[i];
    for (int i = tid; i < 4096; i += 256) wf[320 + i]  = rbW1[i];
    for (int i = tid; i < 64;   i += 256) wf[4416 + i] = rbB1[i];
    __syncthreads();
    if (!pv) return;

    const float* W1 = wf + 320; const float* B1 = wf + 4416;
    float invd = 1.0f / dv;
    const float step = (1.4f - 0.125f) / 63.0f;
    const float gam = 1.0f / (step * step);
    float hid[64];
    #pragma unroll
    for (int j = 0; j < 64; ++j) hid[j] = B1[j];
    for (int i = 0; i < 64; ++i) {
        float c = 0.125f + i * step;
        float d = invd - c;
        float r = __expf(-gam * d * d);
        #pragma unroll
        for (int j = 0; j < 64; ++j) hid[j] += r * W1[i * 64 + j];
    }
    #pragma unroll
    for (int o8 = 0; o8 < 8; ++o8) {
        bf16x8 v;
        #pragma unroll
        for (int j = 0; j < 8; ++j) v[j] = (__bf16)siluf_(hid[o8 * 8 + j]);
        *(bf16x8*)(ea2 + ((size_t)o8 * EP + p) * 16) = v;
    }
    const float* sW1 = wf; const float* sB1 = wf + 288;
    float h2[32];
    #pragma unroll
    for (int j = 0; j < 32; ++j) h2[j] = sB1[j];
    #pragma unroll
    for (int i = 0; i < 9; ++i) {
        float si = shv[i];
        #pragma unroll
        for (int j = 0; j < 32; ++j) h2[j] += si * sW1[i * 32 + j];
    }
    #pragma unroll
    for (int o8 = 0; o8 < 4; ++o8) {
        bf16x8 v;
        #pragma unroll
        for (int j = 0; j < 8; ++j) v[j] = (__bf16)siluf_(h2[o8 * 8 + j]);
        *(bf16x8*)(ea2 + ((size_t)(8 + o8) * EP + p) * 16) = v;
    }
}

// ---------------------------------------------------------------------------
// Per-node GEMM -> SPLIT packed bf16 buffers (full line utilization per side):
// NBd2[node][fq][8] = [gd(4) | cd(4)]   (dst side, 512B/row)
// NBs2[node][fq][8] = [gs(4) | cs(4)]   (src side, 512B/row)
// ---------------------------------------------------------------------------
__global__ void __launch_bounds__(256) k_node(const float* __restrict__ h,
                                              const __bf16* __restrict__ WnT,
                                              const float* __restrict__ bgl,
                                              const float* __restrict__ bcl,
                                              __bf16* __restrict__ NBd2,
                                              __bf16* __restrict__ NBs2, int layer) {
    int tid = threadIdx.x, lane = tid & 63, w = tid >> 6;
    int sub = lane >> 4, rA = lane & 15;
    int node0 = blockIdx.x * 32;
    bf16x8 Bf[2][4];
    #pragma unroll
    for (int nt = 0; nt < 2; ++nt)
        #pragma unroll
        for (int ks = 0; ks < 4; ++ks) {
            int node = min(node0 + nt * 16 + rA, N_NODES - 1);
            const float* hr = h + (size_t)node * 128 + ks * 32 + sub * 8;
            f32x4 u0 = *(const f32x4*)hr;
            f32x4 u1 = *(const f32x4*)(hr + 4);
            bf16x8 bv;
            bv[0] = (__bf16)u0[0]; bv[1] = (__bf16)u0[1];
            bv[2] = (__bf16)u0[2]; bv[3] = (__bf16)u0[3];
            bv[4] = (__bf16)u1[0]; bv[5] = (__bf16)u1[1];
            bv[6] = (__bf16)u1[2]; bv[7] = (__bf16)u1[3];
            Bf[nt][ks] = bv;
        }
    const __bf16* Wbase = WnT + (size_t)layer * 128 * 512;
    f32x4 acc[8][2];
    f32x4 zz = {0.f, 0.f, 0.f, 0.f};
    #pragma unroll
    for (int mt = 0; mt < 8; ++mt) { acc[mt][0] = zz; acc[mt][1] = zz; }
    for (int mt = 0; mt < 8; ++mt) {
        int gm = w * 8 + mt;
        bf16x8 Af[4];
        #pragma unroll
        for (int ks = 0; ks < 4; ++ks)
            Af[ks] = *(const bf16x8*)(Wbase + (size_t)(gm * 4 + ks) * 512 + lane * 8);
        #pragma unroll
        for (int nt = 0; nt < 2; ++nt) {
            f32x4 a = acc[mt][nt];
            #pragma unroll
            for (int ks = 0; ks < 4; ++ks)
                a = __builtin_amdgcn_mfma_f32_16x16x32_bf16(Af[ks], Bf[nt][ks], a, 0, 0, 0);
            acc[mt][nt] = a;
        }
    }
    #pragma unroll
    for (int mt = 0; mt < 8; ++mt) {
        int F = (w * 8 + mt) * 16 + sub * 4;     // global feature 0..511
        int part = F >> 7;                       // 0=gd 1=cd 2=gs 3=cs
        int fq = (F & 127) >> 2;                 // F-group 0..31
        f32x4 bias = zz;
        if (part == 0)      bias = *(const f32x4*)(bgl + (F & 127));
        else if (part == 1) bias = *(const f32x4*)(bcl + (F & 127));
        __bf16* buf = (part < 2) ? NBd2 : NBs2;
        int off = fq * 8 + (part & 1) * 4;
        #pragma unroll
        for (int nt = 0; nt < 2; ++nt) {
            int node = node0 + nt * 16 + rA;
            if (node >= N_NODES) continue;
            f32x4 vv = acc[mt][nt];
            vv[0] += bias[0]; vv[1] += bias[1]; vv[2] += bias[2]; vv[3] += bias[3];
            bf16x4 bv;
            bv[0] = (__bf16)vv[0]; bv[1] = (__bf16)vv[1];
            bv[2] = (__bf16)vv[2]; bv[3] = (__bf16)vv[3];
            *(bf16x4*)(buf + (size_t)node * 256 + off) = bv;
        }
    }
}

// ---------------------------------------------------------------------------
// Message layer, dst-sorted, all blocks full (padded edges -> dummy node).
// Per nt per thread: 3 bfr + 1 dst-NB (16B) + 1 src-NB (16B) + 1 int2 idx.
// ---------------------------------------------------------------------------
__global__ void __launch_bounds__(512) k_msg(
    const char* __restrict__ ea2, const int* __restrict__ dstS,
    const int2* __restrict__ sdS, const __bf16* __restrict__ WeT,
    const __bf16* __restrict__ NBd2, const __bf16* __restrict__ NBs2,
    float* __restrict__ h, int layer)
{
    __shared__ __align__(16) float mF[EB * 128];   // 64 KB messages (XOR-swizzled)
    __shared__ int rs[SPANMAX], re[SPANMAX];
    int tid = threadIdx.x, lane = tid & 63, w = tid >> 6;
    int sub = lane >> 4, rA = lane & 15;
    int e0 = blockIdx.x * EB;
    int fq = w * 4 + sub;                          // F-group 0..31
    int n0 = dstS[e0];

    // run-boundary tables (gap-fill by run-starter; no init barrier needed)
    if (tid < EB) {
        int d = dstS[e0 + tid];
        int di = min(d - n0, SPANMAX - 1);
        if (tid == 0 || dstS[e0 + tid - 1] != d) {
            rs[di] = tid;
            if (tid > 0) {
                int dp = dstS[e0 + tid - 1];
                for (int g = dp + 1; g < d && (g - n0) < SPANMAX; ++g) {
                    rs[g - n0] = 0; re[g - n0] = 0;
                }
            }
        }
        if (tid == EB - 1 || dstS[e0 + tid + 1] != d) re[di] = tid + 1;
    }

    // folded edge-weight A-frags (registers, L2-resident)
    bf16x8 Ag[3], Ac[3];
    {
        const __bf16* bg_ = WeT + (size_t)(((layer * 2 + 0) * 8 + w) * 3) * 512;
        const __bf16* bc_ = WeT + (size_t)(((layer * 2 + 1) * 8 + w) * 3) * 512;
        #pragma unroll
        for (int ks = 0; ks < 3; ++ks) {
            Ag[ks] = *(const bf16x8*)(bg_ + ks * 512 + lane * 8);
            Ac[ks] = *(const bf16x8*)(bc_ + ks * 512 + lane * 8);
        }
    }

    // hoisted loop-invariant bases
    const char* eb0 = ea2 + ((size_t)(0 + sub) * EP + e0 + rA) * 16;
    const char* eb1 = ea2 + ((size_t)(4 + sub) * EP + e0 + rA) * 16;
    const char* eb2 = ea2 + ((size_t)(8 + sub) * EP + e0 + rA) * 16;
    const int2* sdp = sdS + e0 + rA;
    char* mfp = (char*)mF + rA * 512 + ((w * 64 + sub * 16) ^ ((rA & 7) << 4));

    f32x4 zz = {0.f, 0.f, 0.f, 0.f};
    // depth-2 pipelined register sets (indices fold to constants under unroll)
    bf16x8 bfr[2][3];
    bf16x8 dv[2], sv[2];

    // prologue: load nt=0
    {
        int2 sd = sdp[0];
        int dstc = min(sd.x, N_NODES - 1);
        bfr[0][0] = *(const bf16x8*)(eb0);
        bfr[0][1] = *(const bf16x8*)(eb1);
        bfr[0][2] = *(const bf16x8*)(eb2);
        dv[0] = *(const bf16x8*)(NBd2 + (size_t)dstc * 256 + fq * 8);
        sv[0] = *(const bf16x8*)(NBs2 + (size_t)sd.y * 256 + fq * 8);
    }
    #pragma unroll
    for (int nt = 0; nt < EB / 16; ++nt) {
        int cur = nt & 1, nxt = cur ^ 1;
        if (nt + 1 < EB / 16) {   // prefetch next sub-tile
            int2 sd = sdp[(nt + 1) * 16];
            int dstc = min(sd.x, N_NODES - 1);
            bfr[nxt][0] = *(const bf16x8*)(eb0 + (nt + 1) * 256);
            bfr[nxt][1] = *(const bf16x8*)(eb1 + (nt + 1) * 256);
            bfr[nxt][2] = *(const bf16x8*)(eb2 + (nt + 1) * 256);
            dv[nxt] = *(const bf16x8*)(NBd2 + (size_t)dstc * 256 + fq * 8);
            sv[nxt] = *(const bf16x8*)(NBs2 + (size_t)sd.y * 256 + fq * 8);
        }
        f32x4 aG = zz, aC = zz;
        #pragma unroll
        for (int ks = 0; ks < 3; ++ks) {
            aG = __builtin_amdgcn_mfma_f32_16x16x32_bf16(Ag[ks], bfr[cur][ks], aG, 0, 0, 0);
            aC = __builtin_amdgcn_mfma_f32_16x16x32_bf16(Ac[ks], bfr[cur][ks], aC, 0, 0, 0);
        }
        f32x4 mv;
        #pragma unroll
        for (int r = 0; r < 4; ++r) {
            float gi = aG[r] + (float)dv[cur][r] + (float)sv[cur][r];
            float ci = aC[r] + (float)dv[cur][4 + r] + (float)sv[cur][4 + r];
            mv[r] = sigmoidf_(gi) * softplusf_(ci);
        }
        *(f32x4*)(mfp + nt * 8192) = mv;
    }
    __syncthreads();
    // segment-sum over runs -> h (16B feature granularity)
    int span = min(dstS[e0 + EB - 1] - n0 + 1, SPANMAX);
    int items = span * 32;
    for (int it = tid; it < items; it += 512) {
        int ln = it >> 5, fqq = it & 31;
        int rs_ = rs[ln], re_ = re[ln];
        f32x4 s = zz;
        for (int e = rs_; e < re_; ++e) {
            f32x4 v = *(const f32x4*)((char*)mF + e * 512 + ((fqq * 16) ^ ((e & 7) << 4)));
            s[0] += v[0]; s[1] += v[1]; s[2] += v[2]; s[3] += v[3];
        }
        int node = n0 + ln;
        float* dp = h + (size_t)node * 128 + fqq * 4;
        if (ln == 0 || ln == span - 1) {
            atomicAdd(dp + 0, s[0]); atomicAdd(dp + 1, s[1]);
            atomicAdd(dp + 2, s[2]); atomicAdd(dp + 3, s[3]);
        } else {
            dp[0] += s[0]; dp[1] += s[1]; dp[2] += s[2]; dp[3] += s[3];
        }
    }
}

// ---------------------------------------------------------------------------
// Readout
// ---------------------------------------------------------------------------
__global__ void __launch_bounds__(128) k_readout(const float* __restrict__ h,
    const int* __restrict__ batch, const float* __restrict__ W1,
    const float* __restrict__ b1, const float* __restrict__ W2,
    const float* __restrict__ b2, float* __restrict__ out) {
    int g = blockIdx.x, tid = threadIdx.x;
    __shared__ int se[2];
    __shared__ float pl[NF];
    __shared__ float red[2];
    if (tid < 2) {
        int target = g + tid;
        int lo = 0, hi = N_NODES;
        while (lo < hi) { int mid = (lo + hi) >> 1; if (batch[mid] < target) lo = mid + 1; else hi = mid; }
        se[tid] = lo;
    }
    __syncthreads();
    int s = se[0], e = se[1];
    float sum = 0.0f;
    for (int n = s; n < e; ++n) sum += h[(size_t)n * NF + tid];
    float cnt = (float)max(e - s, 1);
    pl[tid] = sum / cnt;
    __syncthreads();
    float acc = b1[tid];
    for (int c = 0; c < NF; ++c) acc += pl[c] * W1[c * NF + tid];
    float hid = siluf_(acc);
    float v = hid * W2[tid];
    #pragma unroll
    for (int off = 32; off > 0; off >>= 1) v += __shfl_down(v, off);
    if ((tid & 63) == 0) red[tid >> 6] = v;
    __syncthreads();
    if (tid == 0) out[g] = red[0] + red[1] + b2[0];
}

// ---------------------------------------------------------------------------
extern "C" void kernel_launch(void* const* d_in, const int* in_sizes, int n_in,
                              void* d_out, int out_size, void* d_ws, size_t ws_size,
                              hipStream_t stream) {
    const float* x     = (const float*)d_in[0];
    const int*   eidx  = (const int*)d_in[1];
    const float* sh    = (const float*)d_in[2];
    const float* edist = (const float*)d_in[3];
    const int*   batch = (const int*)d_in[4];
    const float* W_emb = (const float*)d_in[5];
    const float* b_emb = (const float*)d_in[6];
    const float* shW1  = (const float*)d_in[7];
    const float* shB1  = (const float*)d_in[8];
    const float* shW2  = (const float*)d_in[9];
    const float* shB2  = (const float*)d_in[10];
    const float* rbW1  = (const float*)d_in[11];
    const float* rbB1  = (const float*)d_in[12];
    const float* rbW2  = (const float*)d_in[13];
    const float* rbB2  = (const float*)d_in[14];
    const float* Wg    = (const float*)d_in[15];
    const float* bg    = (const float*)d_in[16];
    const float* Wc    = (const float*)d_in[17];
    const float* bc    = (const float*)d_in[18];
    const float* fcW1  = (const float*)d_in[19];
    const float* fcb1  = (const float*)d_in[20];
    const float* fcW2  = (const float*)d_in[21];
    const float* fcb2  = (const float*)d_in[22];
    const int* srcI = eidx;
    const int* dstI = eidx + N_EDGES;

    char* ws = (char*)d_ws;
    float*  h     = (float*)(ws + 0);              // 25,600,512 (50001 rows; last = dummy)
    char*   ea2   = (char*)(ws + 25600512);        // 96,018,432 (12 planes x EP x 16B)
    int*    dstS  = (int*)(ws + 121618944);        //  2,000,384 (EP entries)
    int2*   sdS   = (int2*)(ws + 123619328);       //  4,000,768 (EP entries)
    int*    deg   = (int*)(ws + 127620096);        //    200,000
    int*    curs  = (int*)(ws + 127820096);        //    200,000
    int*    perm  = (int*)(ws + 128020096);        //  2,000,000
    __bf16* WeT   = (__bf16*)(ws + 130020096);     //    245,760
    __bf16* WnT   = (__bf16*)(ws + 130265856);     //    655,360
    float*  Wfold = (float*)(ws + 130921216);      //    491,520
    float*  bF    = (float*)(ws + 131412736);      //      5,120
    __bf16* NBd2  = (__bf16*)(ws + 131417856);     // 25,600,000
    __bf16* NBs2  = (__bf16*)(ws + 157017856);     // 25,600,000  -> ends 182.6 MB

    hipMemsetAsync(deg, 0, (size_t)N_NODES * sizeof(int), stream);
    k_fold<<<10, 256, 0, stream>>>(Wg, Wc, rbW2, rbB2, shW2, shB2, bg, bc, Wfold, bF);
    k_prep_w<<<220, 256, 0, stream>>>(Wg, Wc, Wfold, WeT, WnT);
    k_embed<<<N_NODES / 8, 256, 0, stream>>>(x, W_emb, b_emb, h);
    k_deg<<<(N_EDGES + 255) / 256, 256, 0, stream>>>(dstI, deg);
    k_scan<<<1, 1024, 0, stream>>>(deg, curs);
    k_scatter<<<(N_EDGES + 255) / 256, 256, 0, stream>>>(srcI, dstI, curs, perm, dstS, sdS);
    k_edge<<<(N_EDGES + 255) / 256, 256, 0, stream>>>(sh, edist, perm, shW1, shB1,
                                                      rbW1, rbB1, ea2);
    k_pad<<<1, 128, 0, stream>>>(dstS, sdS, ea2);
    for (int l = 0; l < N_LAYERS; ++l) {
        const float* bgF = bF + (l * 2 + 0) * 128;
        const float* bcF = bF + (l * 2 + 1) * 128;
        k_node<<<(N_NODES + 31) / 32, 256, 0, stream>>>(h, WnT, bgF, bcF, NBd2, NBs2, l);
        k_msg<<<EP / EB, 512, 0, stream>>>(ea2, dstS, sdS, WeT, NBd2, NBs2, h, l);
    }
    k_readout<<<N_GRAPHS, 128, 0, stream>>>(h, batch, fcW1, fcb1, fcW2, fcb2, (float*)d_out);
}

// Round 15
// 1073.311 us; speedup vs baseline: 1.6012x; 1.0790x over previous
//
#include <hip/hip_runtime.h>

typedef __bf16 bf16x8 __attribute__((ext_vector_type(8)));
typedef __bf16 bf16x4 __attribute__((ext_vector_type(4)));
typedef float  f32x4  __attribute__((ext_vector_type(4)));

#define N_NODES  50000
#define N_EDGES  500000
#define EB       128         // edges per k_msg block
#define EP       500096      // padded edge count (multiple of EB)
#define NCH      12          // 16B chunks per edge row (96 bf16)
#define N_GRAPHS 1024
#define NF       128
#define IN_DIM   92
#define N_LAYERS 5
#define SPANMAX  256

__device__ __forceinline__ float sigmoidf_(float x) { return 1.0f / (1.0f + __expf(-x)); }
__device__ __forceinline__ float softplusf_(float x) {
    return fmaxf(x, 0.0f) + __logf(1.0f + __expf(-fabsf(x)));
}
__device__ __forceinline__ float siluf_(float x) { return x * sigmoidf_(x); }

// ---------------------------------------------------------------------------
// Fold the edge-MLP second stage into layer weights — PARALLEL version:
// one thread per output element (10 lg x 12288 elems = 480 blocks x 256 thr).
// ---------------------------------------------------------------------------
__global__ void __launch_bounds__(256) k_fold(const float* __restrict__ Wg,
    const float* __restrict__ Wc, const float* __restrict__ rbW2,
    const float* __restrict__ rbB2, const float* __restrict__ shW2,
    const float* __restrict__ shB2, const float* __restrict__ bg,
    const float* __restrict__ bc, float* __restrict__ Wfold,
    float* __restrict__ bF) {
    int lg = blockIdx.x / 48, chunk = blockIdx.x % 48;
    int l = lg >> 1, g = lg & 1;
    const float* W = (g ? Wc : Wg) + (size_t)l * 384 * 128;
    int idx = chunk * 256 + threadIdx.x;         // 0..12287
    int r = idx >> 7, n = idx & 127;
    float s = 0.f;
    if (r < 64) {
        for (int o = 0; o < 64; ++o) s += rbW2[r * 64 + o] * W[(256 + o) * 128 + n];
    } else {
        int j = r - 64;
        for (int o = 0; o < 64; ++o) s += shW2[j * 64 + o] * W[(320 + o) * 128 + n];
    }
    Wfold[(size_t)lg * 12288 + idx] = s;
    if (chunk == 0 && threadIdx.x < 128) {
        const float* bsrc = (g ? bc : bg) + l * 128;
        float b = bsrc[threadIdx.x];
        for (int o = 0; o < 64; ++o) b += rbB2[o] * W[(256 + o) * 128 + threadIdx.x];
        for (int o = 0; o < 64; ++o) b += shB2[o] * W[(320 + o) * 128 + threadIdx.x];
        bF[lg * 128 + threadIdx.x] = b;
    }
}

// ---------------------------------------------------------------------------
// Weight prep: WeT = A-frags of Wfold^T; WnT = A-frags of node weights.
// ---------------------------------------------------------------------------
__global__ void __launch_bounds__(256) k_prep_w(const float* __restrict__ Wg,
                                                const float* __restrict__ Wc,
                                                const float* __restrict__ Wfold,
                                                __bf16* __restrict__ WeT,
                                                __bf16* __restrict__ WnT) {
    int t = blockIdx.x * 256 + threadIdx.x;
    if (t >= (240 + 640) * 64) return;
    int frag = t >> 6, lane = t & 63;
    int sub = lane >> 4, mm = lane & 15;
    bf16x8 v;
    if (frag < 240) {
        int lg = frag / 24; int r = frag % 24;
        int m = r / 3; int ks = r % 3;
        #pragma unroll
        for (int j = 0; j < 8; ++j) {
            int k = ks * 32 + sub * 8 + j;
            v[j] = (__bf16)Wfold[(size_t)lg * 12288 + (size_t)k * 128 + m * 16 + mm];
        }
        *(bf16x8*)(WeT + (size_t)frag * 512 + lane * 8) = v;
    } else {
        int f2 = frag - 240;
        int l = f2 / 128; int r = f2 % 128;
        int m = r >> 2; int ks = r & 3;
        int F = m * 16 + mm;
        #pragma unroll
        for (int j = 0; j < 8; ++j) {
            int k = ks * 32 + sub * 8 + j;
            float val;
            if      (F < 128) val = Wg[(size_t)l*384*128 + (size_t)k*128 + F];
            else if (F < 256) val = Wc[(size_t)l*384*128 + (size_t)k*128 + (F-128)];
            else if (F < 384) val = Wg[(size_t)l*384*128 + (size_t)(128+k)*128 + (F-256)];
            else              val = Wc[(size_t)l*384*128 + (size_t)(128+k)*128 + (F-384)];
            v[j] = (__bf16)val;
        }
        *(bf16x8*)(WnT + (size_t)f2 * 512 + lane * 8) = v;
    }
}

// ---------------------------------------------------------------------------
// CSR build
// ---------------------------------------------------------------------------
__global__ void __launch_bounds__(256) k_deg(const int* __restrict__ dstI,
                                             int* __restrict__ deg) {
    int e = blockIdx.x * 256 + threadIdx.x;
    if (e < N_EDGES) atomicAdd(&deg[dstI[e]], 1);
}

__global__ void __launch_bounds__(1024) k_scan(const int* __restrict__ deg,
                                               int* __restrict__ cursor) {
    __shared__ int ps[1024];
    int t = threadIdx.x;
    const int C = (N_NODES + 1023) / 1024;
    int base = t * C;
    int s = 0;
    for (int i = 0; i < C; ++i) { int idx = base + i; if (idx < N_NODES) s += deg[idx]; }
    ps[t] = s;
    __syncthreads();
    for (int off = 1; off < 1024; off <<= 1) {
        int v = 0;
        if (t >= off) v = ps[t - off];
        __syncthreads();
        if (t >= off) ps[t] += v;
        __syncthreads();
    }
    int run = (t > 0) ? ps[t - 1] : 0;
    for (int i = 0; i < C; ++i) {
        int idx = base + i;
        if (idx < N_NODES) { cursor[idx] = run; run += deg[idx]; }
    }
}

// ---------------------------------------------------------------------------
// Scatter: builds sorted dst, pre-scaled (dst,src) offsets, AND gathers the
// per-edge raw features (dist, sh) into sorted order via scattered writes
// (fire-and-forget) so k_edge becomes a pure streaming kernel.
// ---------------------------------------------------------------------------
__global__ void __launch_bounds__(256) k_scatter(const int* __restrict__ srcI,
                                                 const int* __restrict__ dstI,
                                                 const float* __restrict__ edist,
                                                 const float* __restrict__ sh,
                                                 int* __restrict__ cursor,
                                                 int* __restrict__ dstS,
                                                 int2* __restrict__ sdS,
                                                 float* __restrict__ distS,
                                                 float* __restrict__ shS) {
    int e = blockIdx.x * 256 + threadIdx.x;
    if (e >= N_EDGES) return;
    int d = dstI[e];
    int p = atomicAdd(&cursor[d], 1);
    dstS[p] = d;
    sdS[p] = make_int2(d * 256, srcI[e] * 256);
    distS[p] = edist[e];
    #pragma unroll
    for (int i = 0; i < 9; ++i) shS[(size_t)p * 9 + i] = sh[(size_t)e * 9 + i];
}

// ---------------------------------------------------------------------------
// Pad entries [N_EDGES, EP): dummy dst node N_NODES (h row 50000), clamped NB
// offsets, benign dist, zeroed ea2 chunks.
// ---------------------------------------------------------------------------
__global__ void __launch_bounds__(128) k_pad(int* __restrict__ dstS,
                                             int2* __restrict__ sdS,
                                             char* __restrict__ ea2) {
    int i = threadIdx.x;
    if (i < EP - N_EDGES) {
        dstS[N_EDGES + i] = N_NODES;
        sdS[N_EDGES + i] = make_int2((N_NODES - 1) * 256, 0);
        uint4 z = {0, 0, 0, 0};
        for (int p = 0; p < NCH; ++p)
            *(uint4*)(ea2 + ((size_t)p * EP + N_EDGES + i) * 16) = z;
    }
}

// ---------------------------------------------------------------------------
// Atom embedding: h = x @ W_emb + b_emb (f32)
// ---------------------------------------------------------------------------
__global__ void __launch_bounds__(256) k_embed(const float* __restrict__ x,
                                               const float* __restrict__ W,
                                               const float* __restrict__ b,
                                               float* __restrict__ h) {
    int tid = threadIdx.x;
    int f = tid & 127;
    int nb = blockIdx.x * 8 + (tid >> 7) * 4;   // 8 nodes per block
    const float* x0 = x + (size_t)nb * IN_DIM;
    float a0 = b[f], a1 = a0, a2 = a0, a3 = a0;
    #pragma unroll 4
    for (int k = 0; k < IN_DIM; ++k) {
        float wv = W[k * NF + f];
        a0 = fmaf(x0[k], wv, a0);
        a1 = fmaf(x0[IN_DIM + k], wv, a1);
        a2 = fmaf(x0[2 * IN_DIM + k], wv, a2);
        a3 = fmaf(x0[3 * IN_DIM + k], wv, a3);
    }
    float accs[4] = {a0, a1, a2, a3};
    #pragma unroll
    for (int r = 0; r < 4; ++r)
        h[(size_t)(nb + r) * NF + f] = accs[r];
}

// ---------------------------------------------------------------------------
// Edge hidden features eh[e][96] — now fully streaming (sorted inputs),
// transposed chunk-plane output layout.
// ---------------------------------------------------------------------------
__global__ void __launch_bounds__(256) k_edge(const float* __restrict__ distS,
    const float* __restrict__ shS,
    const float* __restrict__ shW1, const float* __restrict__ shB1,
    const float* __restrict__ rbW1, const float* __restrict__ rbB1,
    char* __restrict__ ea2) {
    __shared__ float wf[4480];
    int tid = threadIdx.x;
    int p = blockIdx.x * 256 + tid;
    bool pv = p < N_EDGES;
    int pc = pv ? p : 0;
    float dv = distS[pc];
    float shv[9];
    #pragma unroll
    for (int i = 0; i < 9; ++i) shv[i] = shS[(size_t)pc * 9 + i];
    for (int i = tid; i < 288;  i += 256) wf[i]        = shW1[i];
    for (int i = tid; i < 32;   i += 256) wf[288 + i]  = shB1[i];
    for (int i = tid; i < 4096; i += 256) wf[320 + i]  = rbW1[i];
    for (int i = tid; i < 64;   i += 256) wf[4416 + i] = rbB1[i];
    __syncthreads();
    if (!pv) return;

    const float* W1 = wf + 320; const float* B1 = wf + 4416;
    float invd = 1.0f / dv;
    const float step = (1.4f - 0.125f) / 63.0f;
    const float gam = 1.0f / (step * step);
    float hid[64];
    #pragma unroll
    for (int j = 0; j < 64; ++j) hid[j] = B1[j];
    for (int i = 0; i < 64; ++i) {
        float c = 0.125f + i * step;
        float d = invd - c;
        float r = __expf(-gam * d * d);
        #pragma unroll
        for (int j = 0; j < 64; ++j) hid[j] += r * W1[i * 64 + j];
    }
    #pragma unroll
    for (int o8 = 0; o8 < 8; ++o8) {
        bf16x8 v;
        #pragma unroll
        for (int j = 0; j < 8; ++j) v[j] = (__bf16)siluf_(hid[o8 * 8 + j]);
        *(bf16x8*)(ea2 + ((size_t)o8 * EP + p) * 16) = v;
    }
    const float* sW1 = wf; const float* sB1 = wf + 288;
    float h2[32];
    #pragma unroll
    for (int j = 0; j < 32; ++j) h2[j] = sB1[j];
    #pragma unroll
    for (int i = 0; i < 9; ++i) {
        float si = shv[i];
        #pragma unroll
        for (int j = 0; j < 32; ++j) h2[j] += si * sW1[i * 32 + j];
    }
    #pragma unroll
    for (int o8 = 0; o8 < 4; ++o8) {
        bf16x8 v;
        #pragma unroll
        for (int j = 0; j < 8; ++j) v[j] = (__bf16)siluf_(h2[o8 * 8 + j]);
        *(bf16x8*)(ea2 + ((size_t)(8 + o8) * EP + p) * 16) = v;
    }
}

// ---------------------------------------------------------------------------
// Per-node GEMM -> SPLIT packed bf16 buffers (full line utilization per side):
// NBd2[node][fq][8] = [gd(4) | cd(4)]   (dst side)
// NBs2[node][fq][8] = [gs(4) | cs(4)]   (src side)
// ---------------------------------------------------------------------------
__global__ void __launch_bounds__(256) k_node(const float* __restrict__ h,
                                              const __bf16* __restrict__ WnT,
                                              const float* __restrict__ bgl,
                                              const float* __restrict__ bcl,
                                              __bf16* __restrict__ NBd2,
                                              __bf16* __restrict__ NBs2, int layer) {
    int tid = threadIdx.x, lane = tid & 63, w = tid >> 6;
    int sub = lane >> 4, rA = lane & 15;
    int node0 = blockIdx.x * 32;
    bf16x8 Bf[2][4];
    #pragma unroll
    for (int nt = 0; nt < 2; ++nt)
        #pragma unroll
        for (int ks = 0; ks < 4; ++ks) {
            int node = min(node0 + nt * 16 + rA, N_NODES - 1);
            const float* hr = h + (size_t)node * 128 + ks * 32 + sub * 8;
            f32x4 u0 = *(const f32x4*)hr;
            f32x4 u1 = *(const f32x4*)(hr + 4);
            bf16x8 bv;
            bv[0] = (__bf16)u0[0]; bv[1] = (__bf16)u0[1];
            bv[2] = (__bf16)u0[2]; bv[3] = (__bf16)u0[3];
            bv[4] = (__bf16)u1[0]; bv[5] = (__bf16)u1[1];
            bv[6] = (__bf16)u1[2]; bv[7] = (__bf16)u1[3];
            Bf[nt][ks] = bv;
        }
    const __bf16* Wbase = WnT + (size_t)layer * 128 * 512;
    f32x4 acc[8][2];
    f32x4 zz = {0.f, 0.f, 0.f, 0.f};
    #pragma unroll
    for (int mt = 0; mt < 8; ++mt) { acc[mt][0] = zz; acc[mt][1] = zz; }
    for (int mt = 0; mt < 8; ++mt) {
        int gm = w * 8 + mt;
        bf16x8 Af[4];
        #pragma unroll
        for (int ks = 0; ks < 4; ++ks)
            Af[ks] = *(const bf16x8*)(Wbase + (size_t)(gm * 4 + ks) * 512 + lane * 8);
        #pragma unroll
        for (int nt = 0; nt < 2; ++nt) {
            f32x4 a = acc[mt][nt];
            #pragma unroll
            for (int ks = 0; ks < 4; ++ks)
                a = __builtin_amdgcn_mfma_f32_16x16x32_bf16(Af[ks], Bf[nt][ks], a, 0, 0, 0);
            acc[mt][nt] = a;
        }
    }
    #pragma unroll
    for (int mt = 0; mt < 8; ++mt) {
        int F = (w * 8 + mt) * 16 + sub * 4;     // global feature 0..511
        int part = F >> 7;                       // 0=gd 1=cd 2=gs 3=cs
        int fq = (F & 127) >> 2;                 // F-group 0..31
        f32x4 bias = zz;
        if (part == 0)      bias = *(const f32x4*)(bgl + (F & 127));
        else if (part == 1) bias = *(const f32x4*)(bcl + (F & 127));
        __bf16* buf = (part < 2) ? NBd2 : NBs2;
        int off = fq * 8 + (part & 1) * 4;
        #pragma unroll
        for (int nt = 0; nt < 2; ++nt) {
            int node = node0 + nt * 16 + rA;
            if (node >= N_NODES) continue;
            f32x4 vv = acc[mt][nt];
            vv[0] += bias[0]; vv[1] += bias[1]; vv[2] += bias[2]; vv[3] += bias[3];
            bf16x4 bv;
            bv[0] = (__bf16)vv[0]; bv[1] = (__bf16)vv[1];
            bv[2] = (__bf16)vv[2]; bv[3] = (__bf16)vv[3];
            *(bf16x4*)(buf + (size_t)node * 256 + off) = bv;
        }
    }
}

// ---------------------------------------------------------------------------
// Message layer, dst-sorted, all blocks full (padded edges -> dummy node).
// sdS carries pre-scaled element offsets (dst*256, src*256), pads pre-clamped.
// ---------------------------------------------------------------------------
__global__ void __launch_bounds__(512) k_msg(
    const char* __restrict__ ea2, const int* __restrict__ dstS,
    const int2* __restrict__ sdS, const __bf16* __restrict__ WeT,
    const __bf16* __restrict__ NBd2, const __bf16* __restrict__ NBs2,
    float* __restrict__ h, int layer)
{
    __shared__ __align__(16) float mF[EB * 128];   // 64 KB messages (XOR-swizzled)
    __shared__ int rs[SPANMAX], re[SPANMAX];
    int tid = threadIdx.x, lane = tid & 63, w = tid >> 6;
    int sub = lane >> 4, rA = lane & 15;
    int e0 = blockIdx.x * EB;
    int fq = w * 4 + sub;                          // F-group 0..31
    int n0 = dstS[e0];

    // run-boundary tables (gap-fill by run-starter; no init barrier needed)
    if (tid < EB) {
        int d = dstS[e0 + tid];
        int di = min(d - n0, SPANMAX - 1);
        if (tid == 0 || dstS[e0 + tid - 1] != d) {
            rs[di] = tid;
            if (tid > 0) {
                int dp = dstS[e0 + tid - 1];
                for (int g = dp + 1; g < d && (g - n0) < SPANMAX; ++g) {
                    rs[g - n0] = 0; re[g - n0] = 0;
                }
            }
        }
        if (tid == EB - 1 || dstS[e0 + tid + 1] != d) re[di] = tid + 1;
    }

    // folded edge-weight A-frags (registers, L2-resident)
    bf16x8 Ag[3], Ac[3];
    {
        const __bf16* bg_ = WeT + (size_t)(((layer * 2 + 0) * 8 + w) * 3) * 512;
        const __bf16* bc_ = WeT + (size_t)(((layer * 2 + 1) * 8 + w) * 3) * 512;
        #pragma unroll
        for (int ks = 0; ks < 3; ++ks) {
            Ag[ks] = *(const bf16x8*)(bg_ + ks * 512 + lane * 8);
            Ac[ks] = *(const bf16x8*)(bc_ + ks * 512 + lane * 8);
        }
    }

    // hoisted loop-invariant bases
    const char* eb0 = ea2 + ((size_t)(0 + sub) * EP + e0 + rA) * 16;
    const char* eb1 = ea2 + ((size_t)(4 + sub) * EP + e0 + rA) * 16;
    const char* eb2 = ea2 + ((size_t)(8 + sub) * EP + e0 + rA) * 16;
    const int2* sdp = sdS + e0 + rA;
    const __bf16* nbd = NBd2 + fq * 8;
    const __bf16* nbs = NBs2 + fq * 8;
    char* mfp = (char*)mF + rA * 512 + ((w * 64 + sub * 16) ^ ((rA & 7) << 4));

    f32x4 zz = {0.f, 0.f, 0.f, 0.f};
    // depth-2 pipelined register sets (indices fold to constants under unroll)
    bf16x8 bfr[2][3];
    bf16x8 dv[2], sv[2];

    // prologue: load nt=0
    {
        int2 sd = sdp[0];
        bfr[0][0] = *(const bf16x8*)(eb0);
        bfr[0][1] = *(const bf16x8*)(eb1);
        bfr[0][2] = *(const bf16x8*)(eb2);
        dv[0] = *(const bf16x8*)(nbd + sd.x);
        sv[0] = *(const bf16x8*)(nbs + sd.y);
    }
    #pragma unroll
    for (int nt = 0; nt < EB / 16; ++nt) {
        int cur = nt & 1, nxt = cur ^ 1;
        if (nt + 1 < EB / 16) {   // prefetch next sub-tile
            int2 sd = sdp[(nt + 1) * 16];
            bfr[nxt][0] = *(const bf16x8*)(eb0 + (nt + 1) * 256);
            bfr[nxt][1] = *(const bf16x8*)(eb1 + (nt + 1) * 256);
            bfr[nxt][2] = *(const bf16x8*)(eb2 + (nt + 1) * 256);
            dv[nxt] = *(const bf16x8*)(nbd + sd.x);
            sv[nxt] = *(const bf16x8*)(nbs + sd.y);
        }
        f32x4 aG = zz, aC = zz;
        #pragma unroll
        for (int ks = 0; ks < 3; ++ks) {
            aG = __builtin_amdgcn_mfma_f32_16x16x32_bf16(Ag[ks], bfr[cur][ks], aG, 0, 0, 0);
            aC = __builtin_amdgcn_mfma_f32_16x16x32_bf16(Ac[ks], bfr[cur][ks], aC, 0, 0, 0);
        }
        f32x4 mv;
        #pragma unroll
        for (int r = 0; r < 4; ++r) {
            float gi = aG[r] + (float)dv[cur][r] + (float)sv[cur][r];
            float ci = aC[r] + (float)dv[cur][4 + r] + (float)sv[cur][4 + r];
            mv[r] = sigmoidf_(gi) * softplusf_(ci);
        }
        *(f32x4*)(mfp + nt * 8192) = mv;
    }
    __syncthreads();
    // segment-sum over runs -> h (16B feature granularity)
    int span = min(dstS[e0 + EB - 1] - n0 + 1, SPANMAX);
    int items = span * 32;
    for (int it = tid; it < items; it += 512) {
        int ln = it >> 5, fqq = it & 31;
        int rs_ = rs[ln], re_ = re[ln];
        f32x4 s = zz;
        for (int e = rs_; e < re_; ++e) {
            f32x4 v = *(const f32x4*)((char*)mF + e * 512 + ((fqq * 16) ^ ((e & 7) << 4)));
            s[0] += v[0]; s[1] += v[1]; s[2] += v[2]; s[3] += v[3];
        }
        int node = n0 + ln;
        float* dp = h + (size_t)node * 128 + fqq * 4;
        if (ln == 0 || ln == span - 1) {
            atomicAdd(dp + 0, s[0]); atomicAdd(dp + 1, s[1]);
            atomicAdd(dp + 2, s[2]); atomicAdd(dp + 3, s[3]);
        } else {
            dp[0] += s[0]; dp[1] += s[1]; dp[2] += s[2]; dp[3] += s[3];
        }
    }
}

// ---------------------------------------------------------------------------
// Readout
// ---------------------------------------------------------------------------
__global__ void __launch_bounds__(128) k_readout(const float* __restrict__ h,
    const int* __restrict__ batch, const float* __restrict__ W1,
    const float* __restrict__ b1, const float* __restrict__ W2,
    const float* __restrict__ b2, float* __restrict__ out) {
    int g = blockIdx.x, tid = threadIdx.x;
    __shared__ int se[2];
    __shared__ float pl[NF];
    __shared__ float red[2];
    if (tid < 2) {
        int target = g + tid;
        int lo = 0, hi = N_NODES;
        while (lo < hi) { int mid = (lo + hi) >> 1; if (batch[mid] < target) lo = mid + 1; else hi = mid; }
        se[tid] = lo;
    }
    __syncthreads();
    int s = se[0], e = se[1];
    float sum = 0.0f;
    for (int n = s; n < e; ++n) sum += h[(size_t)n * NF + tid];
    float cnt = (float)max(e - s, 1);
    pl[tid] = sum / cnt;
    __syncthreads();
    float acc = b1[tid];
    for (int c = 0; c < NF; ++c) acc += pl[c] * W1[c * NF + tid];
    float hid = siluf_(acc);
    float v = hid * W2[tid];
    #pragma unroll
    for (int off = 32; off > 0; off >>= 1) v += __shfl_down(v, off);
    if ((tid & 63) == 0) red[tid >> 6] = v;
    __syncthreads();
    if (tid == 0) out[g] = red[0] + red[1] + b2[0];
}

// ---------------------------------------------------------------------------
extern "C" void kernel_launch(void* const* d_in, const int* in_sizes, int n_in,
                              void* d_out, int out_size, void* d_ws, size_t ws_size,
                              hipStream_t stream) {
    const float* x     = (const float*)d_in[0];
    const int*   eidx  = (const int*)d_in[1];
    const float* sh    = (const float*)d_in[2];
    const float* edist = (const float*)d_in[3];
    const int*   batch = (const int*)d_in[4];
    const float* W_emb = (const float*)d_in[5];
    const float* b_emb = (const float*)d_in[6];
    const float* shW1  = (const float*)d_in[7];
    const float* shB1  = (const float*)d_in[8];
    const float* shW2  = (const float*)d_in[9];
    const float* shB2  = (const float*)d_in[10];
    const float* rbW1  = (const float*)d_in[11];
    const float* rbB1  = (const float*)d_in[12];
    const float* rbW2  = (const float*)d_in[13];
    const float* rbB2  = (const float*)d_in[14];
    const float* Wg    = (const float*)d_in[15];
    const float* bg    = (const float*)d_in[16];
    const float* Wc    = (const float*)d_in[17];
    const float* bc    = (const float*)d_in[18];
    const float* fcW1  = (const float*)d_in[19];
    const float* fcb1  = (const float*)d_in[20];
    const float* fcW2  = (const float*)d_in[21];
    const float* fcb2  = (const float*)d_in[22];
    const int* srcI = eidx;
    const int* dstI = eidx + N_EDGES;

    char* ws = (char*)d_ws;
    float*  h     = (float*)(ws + 0);              // 25,600,512 (50001 rows; last = dummy)
    char*   ea2   = (char*)(ws + 25600512);        // 96,018,432 (12 planes x EP x 16B)
    int*    dstS  = (int*)(ws + 121618944);        //  2,000,384 (EP entries)
    int2*   sdS   = (int2*)(ws + 123619328);       //  4,000,768 (EP entries, elem offsets)
    int*    deg   = (int*)(ws + 127620096);        //    200,000
    int*    curs  = (int*)(ws + 127820096);        //    200,000
    float*  distS = (float*)(ws + 128020096);      //  2,000,384
    float*  shS   = (float*)(ws + 130020480);      // 18,003,456
    __bf16* WeT   = (__bf16*)(ws + 148023936);     //    245,760
    __bf16* WnT   = (__bf16*)(ws + 148269696);     //    655,360
    float*  Wfold = (float*)(ws + 148925056);      //    491,520
    float*  bF    = (float*)(ws + 149416576);      //      5,120
    __bf16* NBd2  = (__bf16*)(ws + 149421696);     // 25,600,000
    __bf16* NBs2  = (__bf16*)(ws + 175021696);     // 25,600,000  -> ends 200.6 MB

    hipMemsetAsync(deg, 0, (size_t)N_NODES * sizeof(int), stream);
    k_fold<<<480, 256, 0, stream>>>(Wg, Wc, rbW2, rbB2, shW2, shB2, bg, bc, Wfold, bF);
    k_prep_w<<<220, 256, 0, stream>>>(Wg, Wc, Wfold, WeT, WnT);
    k_embed<<<N_NODES / 8, 256, 0, stream>>>(x, W_emb, b_emb, h);
    k_deg<<<(N_EDGES + 255) / 256, 256, 0, stream>>>(dstI, deg);
    k_scan<<<1, 1024, 0, stream>>>(deg, curs);
    k_scatter<<<(N_EDGES + 255) / 256, 256, 0, stream>>>(srcI, dstI, edist, sh, curs,
                                                         dstS, sdS, distS, shS);
    k_edge<<<(N_EDGES + 255) / 256, 256, 0, stream>>>(distS, shS, shW1, shB1,
                                                      rbW1, rbB1, ea2);
    k_pad<<<1, 128, 0, stream>>>(dstS, sdS, ea2);
    for (int l = 0; l < N_LAYERS; ++l) {
        const float* bgF = bF + (l * 2 + 0) * 128;
        const float* bcF = bF + (l * 2 + 1) * 128;
        k_node<<<(N_NODES + 31) / 32, 256, 0, stream>>>(h, WnT, bgF, bcF, NBd2, NBs2, l);
        k_msg<<<EP / EB, 512, 0, stream>>>(ea2, dstS, sdS, WeT, NBd2, NBs2, h, l);
    }
    k_readout<<<N_GRAPHS, 128, 0, stream>>>(h, batch, fcW1, fcb1, fcW2, fcb2, (float*)d_out);
}